// Round 1
// baseline (1631.139 us; speedup 1.0000x reference)
//
#include <hip/hip_runtime.h>
#include <math.h>

#define B_ 2
#define SEQ_ 4096
#define ST_ 128
#define T_ 4352
#define DIN_ 1024

// ws layout (float offsets)
#define WT4_OFF 0                 // 6 * 1024 * 64 = 393216 floats, [m][i4][o][c]
#define Q_OFF   393216            // [B][T][64]
#define KT_OFF  950272            // [B][d4][T][4]  (k transposed, float4-interleaved)
#define V_OFF   1507328           // [B][T][64]
// total = 2,064,384 floats = 8.26 MB

__device__ __forceinline__ int wuid() {
  return __builtin_amdgcn_readfirstlane((int)(threadIdx.x >> 6));
}

// ---------------- W -> WT4 permute ----------------
__global__ __launch_bounds__(256) void wtrans_kernel(
    const float* __restrict__ Wq,  const float* __restrict__ Wk,
    const float* __restrict__ Wv,  const float* __restrict__ Wqs,
    const float* __restrict__ Wks, const float* __restrict__ Wvs,
    float* __restrict__ ws) {
  const int m = blockIdx.y;   // 0=Wq 1=Wqs 2=Wk 3=Wks 4=Wv 5=Wvs
  const float* src = (m==0)?Wq:(m==1)?Wqs:(m==2)?Wk:(m==3)?Wks:(m==4)?Wv:Wvs;
  float* dst = ws + WT4_OFF + (size_t)m * (DIN_*64);
  const int bx = blockIdx.x;  // 16 blocks, each 64 input-cols
  #pragma unroll
  for (int p = 0; p < 16; ++p) {
    int e = (int)threadIdx.x + (p << 8);
    int c = e & 3, o = (e >> 2) & 63;
    int i = (bx << 6) + (p << 2) + c;
    dst[(((bx << 4) + p) * 64 + o) * 4 + c] = src[o * DIN_ + i];
  }
}

// ---------------- projections + l2norm ----------------
__global__ __launch_bounds__(256) void proj_kernel(
    const float* __restrict__ x, float* __restrict__ ws) {
  __shared__ float tile[32][65];
  const int t0 = blockIdx.x << 5;
  const int b  = blockIdx.y;
  const int pj = blockIdx.z;          // 0=q 1=k 2=v
  const int spec = (t0 < ST_ || t0 >= ST_ + SEQ_) ? 1 : 0;
  const float4* W4 = reinterpret_cast<const float4*>(ws + WT4_OFF + (size_t)(pj*2 + spec) * (DIN_*64));
  const int lane = (int)threadIdx.x & 63;
  const int w = wuid();
  const float* xb = x + ((size_t)(b * T_ + t0 + (w << 3))) * DIN_;
  float acc[8] = {0.f,0.f,0.f,0.f,0.f,0.f,0.f,0.f};
  #pragma unroll 4
  for (int i4 = 0; i4 < 256; ++i4) {
    float4 wv = W4[(i4 << 6) + lane];
    #pragma unroll
    for (int r = 0; r < 8; ++r) {
      float4 xv = reinterpret_cast<const float4*>(xb + r * DIN_)[i4];  // wave-uniform -> s_load
      acc[r] = fmaf(wv.x, xv.x, fmaf(wv.y, xv.y, fmaf(wv.z, xv.z, fmaf(wv.w, xv.w, acc[r]))));
    }
  }
  float outv[8];
  #pragma unroll
  for (int r = 0; r < 8; ++r) {
    float sq = acc[r] * acc[r];
    #pragma unroll
    for (int off = 32; off; off >>= 1) sq += __shfl_xor(sq, off, 64);
    float n = fmaxf(sqrtf(sq), 1e-12f);
    outv[r] = acc[r] / n;
  }
  const int trow = t0 + (w << 3);
  if (pj != 1) {
    float* dst = ws + (pj == 0 ? Q_OFF : V_OFF) + ((size_t)(b * T_ + trow)) * 64;
    #pragma unroll
    for (int r = 0; r < 8; ++r) dst[r * 64 + lane] = outv[r];
  } else {
    #pragma unroll
    for (int r = 0; r < 8; ++r) tile[(w << 3) + r][lane] = outv[r];
    __syncthreads();
    float* kt = ws + KT_OFF + (size_t)b * 16 * T_ * 4;
    #pragma unroll
    for (int p = 0; p < 8; ++p) {
      int e = (int)threadIdx.x + (p << 8);
      int c = e & 3, tt = (e >> 2) & 31, d4 = e >> 7;
      kt[((size_t)d4 * T_ + t0 + tt) * 4 + c] = tile[tt][(d4 << 2) + c];
    }
  }
}

// ---------------- fused attention ----------------
__global__ __launch_bounds__(256) void attn_kernel(
    const float* __restrict__ ws_c, const float* __restrict__ cope,
    const float* __restrict__ scalep, float* __restrict__ out) {
  __shared__ float li[8 * T_];        // 139,264 B : logits_int rows
  __shared__ float pbuf[4][8][64];    // 8 KB : per-wave p transpose / final acc merge
  __shared__ double tot2[2][4][8];    // per-tile per-wave per-row gate totals (dbuf)
  __shared__ float ml[4][8][2];       // final softmax merge (m, lsum)
  const int t0 = blockIdx.x << 3;
  const int b  = blockIdx.y;
  const int lane = (int)threadIdx.x & 63;
  const int w = wuid();
  const float* qrow = ws_c + Q_OFF + ((size_t)(b * T_ + t0)) * 64;   // wave-uniform -> s_load
  const float* ktb  = ws_c + KT_OFF + (size_t)b * 16 * T_ * 4;
  const float* vb   = ws_c + V_OFF + ((size_t)b * T_) * 64;
  const float sc = scalep[0];

  // ---- phase 1: logits_int rows (q . cope) into LDS ----
  for (int jt = 0; jt < 17; ++jt) {
    const int l = (jt << 8) + (w << 6) + lane;
    float a[8] = {0,0,0,0,0,0,0,0};
    #pragma unroll 4
    for (int d4 = 0; d4 < 16; ++d4) {
      float c0 = cope[(d4 * 4 + 0) * T_ + l];
      float c1 = cope[(d4 * 4 + 1) * T_ + l];
      float c2 = cope[(d4 * 4 + 2) * T_ + l];
      float c3 = cope[(d4 * 4 + 3) * T_ + l];
      #pragma unroll
      for (int r = 0; r < 8; ++r) {
        float4 qq = *reinterpret_cast<const float4*>(qrow + r * 64 + (d4 << 2));
        a[r] = fmaf(c0, qq.x, fmaf(c1, qq.y, fmaf(c2, qq.z, fmaf(c3, qq.w, a[r]))));
      }
    }
    #pragma unroll
    for (int r = 0; r < 8; ++r) li[r * T_ + l] = a[r];
  }
  __syncthreads();

  // ---- phase 2: right-to-left sweep over s-tiles of 256 ----
  float m_[8], ls[8], acc[8];
  double carry[8];
  #pragma unroll
  for (int r = 0; r < 8; ++r) { m_[r] = -INFINITY; ls[r] = 0.f; acc[r] = 0.f; carry[r] = 0.0; }
  int buf = 0;

  for (int jt = 16; jt >= 0; --jt) {
    const int s = (jt << 8) + (w << 6) + lane;
    // logits for 8 rows
    float lg[8] = {0,0,0,0,0,0,0,0};
    #pragma unroll 4
    for (int d4 = 0; d4 < 16; ++d4) {
      float4 kk = *reinterpret_cast<const float4*>(ktb + ((size_t)d4 * T_ + s) * 4);
      #pragma unroll
      for (int r = 0; r < 8; ++r) {
        float4 qq = *reinterpret_cast<const float4*>(qrow + r * 64 + (d4 << 2));
        lg[r] = fmaf(kk.x, qq.x, fmaf(kk.y, qq.y, fmaf(kk.z, qq.z, fmaf(kk.w, qq.w, lg[r]))));
      }
    }
    // sigmoid + per-row wave inclusive scan (fp64 carries)
    float g[8]; double inc[8], tt_[8];
    #pragma unroll
    for (int r = 0; r < 8; ++r) {
      g[r] = 1.f / (1.f + __expf(-lg[r]));
      double xx = (double)g[r];
      #pragma unroll
      for (int off = 1; off < 64; off <<= 1) {
        double y = __shfl_up(xx, off, 64);
        if (lane >= off) xx += y;
      }
      inc[r] = xx;
      tt_[r] = __shfl(xx, 63, 64);
    }
    if (lane == 0) {
      #pragma unroll
      for (int r = 0; r < 8; ++r) tot2[buf][w][r] = tt_[r];
    }
    __syncthreads();

    const int causal = ((jt << 8) <= t0 + 7);
    #pragma unroll
    for (int r = 0; r < 8; ++r) {
      double cw = carry[r];
      for (int w2 = w + 1; w2 < 4; ++w2) cw += tot2[buf][w2][r];
      double posd = cw + (tt_[r] - inc[r] + (double)g[r]);   // inclusive suffix
      carry[r] += tot2[buf][0][r] + tot2[buf][1][r] + tot2[buf][2][r] + tot2[buf][3][r];
      if (causal) {
        if (posd > 4351.0) posd = 4351.0;
        int idx = (int)posd;                 // floor (posd >= 0)
        float wf = (float)(posd - (double)idx);
        int idx2 = idx < 4351 ? idx + 1 : 4351;
        float lf = li[r * T_ + idx];
        float lc = li[r * T_ + idx2];
        float bias = fmaf(wf, lc - lf, lf);
        const int t = t0 + r;
        const bool valid = (s <= t) && !((t >= ST_ + SEQ_) && (s < ST_));
        float score = valid ? fmaf(lg[r], sc, bias) : -INFINITY;
        float tmax = score;
        #pragma unroll
        for (int off = 32; off; off >>= 1) tmax = fmaxf(tmax, __shfl_xor(tmax, off, 64));
        float p = 0.f;
        if (tmax != -INFINITY) {
          float mnew = fmaxf(m_[r], tmax);
          float resc = __expf(m_[r] - mnew);   // -inf -> 0
          p = __expf(score - mnew);            // score=-inf -> 0
          float psum = p;
          #pragma unroll
          for (int off = 32; off; off >>= 1) psum += __shfl_xor(psum, off, 64);
          ls[r] = fmaf(ls[r], resc, psum);
          acc[r] *= resc;
          m_[r] = mnew;
        }
        pbuf[w][r][lane] = p;   // wave-private transpose buffer
      }
    }
    if (causal) {
      #pragma unroll 4
      for (int s4 = 0; s4 < 16; ++s4) {
        const int sb = (jt << 8) + (w << 6) + (s4 << 2);
        float v0 = vb[((size_t)(sb + 0)) * 64 + lane];
        float v1 = vb[((size_t)(sb + 1)) * 64 + lane];
        float v2 = vb[((size_t)(sb + 2)) * 64 + lane];
        float v3 = vb[((size_t)(sb + 3)) * 64 + lane];
        #pragma unroll
        for (int r = 0; r < 8; ++r) {
          float4 pr = *reinterpret_cast<const float4*>(&pbuf[w][r][s4 << 2]);
          acc[r] = fmaf(pr.x, v0, fmaf(pr.y, v1, fmaf(pr.z, v2, fmaf(pr.w, v3, acc[r]))));
        }
      }
    }
    buf ^= 1;
  }

  // ---- cross-wave flash merge ----
  if (lane == 0) {
    #pragma unroll
    for (int r = 0; r < 8; ++r) { ml[w][r][0] = m_[r]; ml[w][r][1] = ls[r]; }
  }
  __syncthreads();
  float L[8], mstar[8];
  #pragma unroll
  for (int r = 0; r < 8; ++r) {
    float mm = fmaxf(fmaxf(ml[0][r][0], ml[1][r][0]), fmaxf(ml[2][r][0], ml[3][r][0]));
    mstar[r] = mm;
    L[r] = ml[0][r][1] * __expf(ml[0][r][0] - mm) + ml[1][r][1] * __expf(ml[1][r][0] - mm)
         + ml[2][r][1] * __expf(ml[2][r][0] - mm) + ml[3][r][1] * __expf(ml[3][r][0] - mm);
  }
  #pragma unroll
  for (int r = 0; r < 8; ++r) pbuf[w][r][lane] = acc[r] * __expf(m_[r] - mstar[r]);
  __syncthreads();
  #pragma unroll
  for (int rr = 0; rr < 2; ++rr) {
    const int r = (w << 1) + rr;
    float o = pbuf[0][r][lane] + pbuf[1][r][lane] + pbuf[2][r][lane] + pbuf[3][r][lane];
    out[((size_t)(b * T_ + t0 + r)) * 64 + lane] = o / L[r];
  }
}

extern "C" void kernel_launch(void* const* d_in, const int* in_sizes, int n_in,
                              void* d_out, int out_size, void* d_ws, size_t ws_size,
                              hipStream_t stream) {
  const float* x    = (const float*)d_in[0];
  const float* Wq   = (const float*)d_in[1];
  const float* Wk   = (const float*)d_in[2];
  const float* Wv   = (const float*)d_in[3];
  const float* Wqs  = (const float*)d_in[4];
  const float* Wks  = (const float*)d_in[5];
  const float* Wvs  = (const float*)d_in[6];
  const float* cope = (const float*)d_in[7];
  const float* scl  = (const float*)d_in[8];
  float* ws   = (float*)d_ws;
  float* outp = (float*)d_out;
  (void)in_sizes; (void)n_in; (void)out_size; (void)ws_size;

  hipLaunchKernelGGL(wtrans_kernel, dim3(16, 6), dim3(256), 0, stream,
                     Wq, Wk, Wv, Wqs, Wks, Wvs, ws);
  hipLaunchKernelGGL(proj_kernel, dim3(136, 2, 3), dim3(256), 0, stream, x, ws);
  hipLaunchKernelGGL(attn_kernel, dim3(544, 2), dim3(256), 0, stream, ws, cope, scl, outp);
}

// Round 2
// 709.563 us; speedup vs baseline: 2.2988x; 2.2988x over previous
//
#include <hip/hip_runtime.h>
#include <math.h>

#define B_ 2
#define SEQ_ 4096
#define ST_ 128
#define T_ 4352
#define DIN_ 1024
#define NW 16

// ws layout (float offsets)
#define WT4_OFF 0                 // 6 * 1024 * 64 floats, [m][i4][o][c]
#define Q_OFF   393216            // [B][T][64]
#define KT_OFF  950272            // [B][d4][T][4]
#define V_OFF   1507328           // [B][T][64]

__device__ __forceinline__ int wuid() {
  return __builtin_amdgcn_readfirstlane((int)(threadIdx.x >> 6));
}

// rocPRIM-style wave64 f32 inclusive scan, pure DPP (VALU pipe)
template<int CTRL, int RM>
__device__ __forceinline__ float dppadd(float x) {
  int y = __builtin_amdgcn_update_dpp(0, __float_as_int(x), CTRL, RM, 0xf, true);
  return x + __int_as_float(y);
}
__device__ __forceinline__ float wave_iscan(float x) {
  x = dppadd<0x111, 0xf>(x);   // row_shr:1
  x = dppadd<0x112, 0xf>(x);   // row_shr:2
  x = dppadd<0x114, 0xf>(x);   // row_shr:4
  x = dppadd<0x118, 0xf>(x);   // row_shr:8
  x = dppadd<0x142, 0xa>(x);   // row_bcast:15 -> rows 1,3
  x = dppadd<0x143, 0xc>(x);   // row_bcast:31 -> rows 2,3
  return x;
}

// ---------------- W -> WT4 permute ----------------
__global__ __launch_bounds__(256) void wtrans_kernel(
    const float* __restrict__ Wq,  const float* __restrict__ Wk,
    const float* __restrict__ Wv,  const float* __restrict__ Wqs,
    const float* __restrict__ Wks, const float* __restrict__ Wvs,
    float* __restrict__ ws) {
  const int m = blockIdx.y;
  const float* src = (m==0)?Wq:(m==1)?Wqs:(m==2)?Wk:(m==3)?Wks:(m==4)?Wv:Wvs;
  float* dst = ws + WT4_OFF + (size_t)m * (DIN_*64);
  const int bx = blockIdx.x;
  #pragma unroll
  for (int p = 0; p < 16; ++p) {
    int e = (int)threadIdx.x + (p << 8);
    int c = e & 3, o = (e >> 2) & 63;
    int i = (bx << 6) + (p << 2) + c;
    dst[(((bx << 4) + p) * 64 + o) * 4 + c] = src[o * DIN_ + i];
  }
}

// ---------------- projections + l2norm ----------------
__global__ __launch_bounds__(256) void proj_kernel(
    const float* __restrict__ x, float* __restrict__ ws) {
  __shared__ float tile[32][65];
  const int t0 = blockIdx.x << 5;
  const int b  = blockIdx.y;
  const int pj = blockIdx.z;
  const int spec = (t0 < ST_ || t0 >= ST_ + SEQ_) ? 1 : 0;
  const float4* W4 = reinterpret_cast<const float4*>(ws + WT4_OFF + (size_t)(pj*2 + spec) * (DIN_*64));
  const int lane = (int)threadIdx.x & 63;
  const int w = wuid();
  const float* xb = x + ((size_t)(b * T_ + t0 + (w << 3))) * DIN_;
  float acc[8] = {0.f,0.f,0.f,0.f,0.f,0.f,0.f,0.f};
  #pragma unroll 4
  for (int i4 = 0; i4 < 256; ++i4) {
    float4 wv = W4[(i4 << 6) + lane];
    #pragma unroll
    for (int r = 0; r < 8; ++r) {
      float4 xv = reinterpret_cast<const float4*>(xb + r * DIN_)[i4];
      acc[r] = fmaf(wv.x, xv.x, fmaf(wv.y, xv.y, fmaf(wv.z, xv.z, fmaf(wv.w, xv.w, acc[r]))));
    }
  }
  float outv[8];
  #pragma unroll
  for (int r = 0; r < 8; ++r) {
    float sq = acc[r] * acc[r];
    #pragma unroll
    for (int off = 32; off; off >>= 1) sq += __shfl_xor(sq, off, 64);
    float n = fmaxf(sqrtf(sq), 1e-12f);
    outv[r] = acc[r] / n;
  }
  const int trow = t0 + (w << 3);
  if (pj != 1) {
    float* dst = ws + (pj == 0 ? Q_OFF : V_OFF) + ((size_t)(b * T_ + trow)) * 64;
    #pragma unroll
    for (int r = 0; r < 8; ++r) dst[r * 64 + lane] = outv[r];
  } else {
    #pragma unroll
    for (int r = 0; r < 8; ++r) tile[(w << 3) + r][lane] = outv[r];
    __syncthreads();
    float* kt = ws + KT_OFF + (size_t)b * 16 * T_ * 4;
    #pragma unroll
    for (int p = 0; p < 8; ++p) {
      int e = (int)threadIdx.x + (p << 8);
      int c = e & 3, tt = (e >> 2) & 31, d4 = e >> 7;
      kt[((size_t)d4 * T_ + t0 + tt) * 4 + c] = tile[tt][(d4 << 2) + c];
    }
  }
}

// ---------------- fused attention ----------------
__global__ __launch_bounds__(1024) void attn_kernel(
    const float* __restrict__ ws_c, const float* __restrict__ cope,
    const float* __restrict__ scalep, float* __restrict__ out) {
  __shared__ float li[8 * T_];          // 139264 B
  __shared__ float pbuf[NW][8][32];     // 16384 B
  __shared__ float totF[NW][8];
  __shared__ double suffD[NW][8];
  __shared__ double carryD[2][8];
  __shared__ float mlL[NW][8];
  __shared__ float wmax[NW][8];

  const int tid = (int)threadIdx.x;
  const int lane = tid & 63;
  const int w = wuid();
  const int t0 = ((int)(gridDim.x - 1 - blockIdx.x)) << 3;   // slowest blocks first
  const int b  = blockIdx.y;
  const float* qrow = ws_c + Q_OFF + ((size_t)(b * T_ + t0)) * 64;
  const float* ktb  = ws_c + KT_OFF + (size_t)b * 16 * T_ * 4;
  const float* vb   = ws_c + V_OFF + ((size_t)b * T_) * 64;
  const float sc = scalep[0];

  if (tid < 8) carryD[0][tid] = 0.0;

  // ---- phase 1: logits_int rows into LDS + per-row max ----
  float lm[8];
  #pragma unroll
  for (int r = 0; r < 8; ++r) lm[r] = -INFINITY;
  for (int jt = 0; jt < 5; ++jt) {
    const int l = (jt << 10) + tid;
    if (l < T_) {
      float a[8] = {0,0,0,0,0,0,0,0};
      #pragma unroll 4
      for (int d4 = 0; d4 < 16; ++d4) {
        float c0 = cope[(d4 * 4 + 0) * T_ + l];
        float c1 = cope[(d4 * 4 + 1) * T_ + l];
        float c2 = cope[(d4 * 4 + 2) * T_ + l];
        float c3 = cope[(d4 * 4 + 3) * T_ + l];
        #pragma unroll
        for (int r = 0; r < 8; ++r) {
          float4 qq = *reinterpret_cast<const float4*>(qrow + r * 64 + (d4 << 2));
          a[r] = fmaf(c0, qq.x, fmaf(c1, qq.y, fmaf(c2, qq.z, fmaf(c3, qq.w, a[r]))));
        }
      }
      #pragma unroll
      for (int r = 0; r < 8; ++r) { li[r * T_ + l] = a[r]; lm[r] = fmaxf(lm[r], a[r]); }
    }
  }
  #pragma unroll
  for (int r = 0; r < 8; ++r) {
    #pragma unroll
    for (int off = 32; off; off >>= 1) lm[r] = fmaxf(lm[r], __shfl_xor(lm[r], off, 64));
  }
  if (lane == 0) {
    #pragma unroll
    for (int r = 0; r < 8; ++r) wmax[w][r] = lm[r];
  }
  __syncthreads();
  float mrow[8];
  #pragma unroll
  for (int r = 0; r < 8; ++r) {
    float mm = wmax[0][r];
    #pragma unroll
    for (int w2 = 1; w2 < NW; ++w2) mm = fmaxf(mm, wmax[w2][r]);
    mrow[r] = mm + fabsf(sc) + 1e-3f;   // static safe upper bound on score
  }

  // ---- phase 2: right-to-left sweep, s-tiles of 1024 ----
  float acc[8]  = {0,0,0,0,0,0,0,0};
  float lsum[8] = {0,0,0,0,0,0,0,0};
  int par = 0;
  for (int jt = 4; jt >= 0; --jt) {
    const int s = (jt << 10) + tid;
    const bool sval = (s < T_);
    float lg[8] = {0,0,0,0,0,0,0,0};
    if (sval) {
      #pragma unroll 4
      for (int d4 = 0; d4 < 16; ++d4) {
        float4 kk = *reinterpret_cast<const float4*>(ktb + ((size_t)d4 * T_ + s) * 4);
        #pragma unroll
        for (int r = 0; r < 8; ++r) {
          float4 qq = *reinterpret_cast<const float4*>(qrow + r * 64 + (d4 << 2));
          lg[r] = fmaf(kk.x, qq.x, fmaf(kk.y, qq.y, fmaf(kk.z, qq.z, fmaf(kk.w, qq.w, lg[r]))));
        }
      }
    }
    float locsuf[8], gtot[8];
    #pragma unroll
    for (int r = 0; r < 8; ++r) {
      float g = sval ? 1.f / (1.f + __expf(-lg[r])) : 0.f;
      float xx = wave_iscan(g);
      float tt = __shfl(xx, 63, 64);
      locsuf[r] = tt - xx + g;   // inclusive suffix within wave
      gtot[r] = tt;
    }
    if (lane == 0) {
      #pragma unroll
      for (int r = 0; r < 8; ++r) totF[w][r] = gtot[r];
    }
    __syncthreads();
    if (tid < 128) {
      const int w2 = tid >> 3, r = tid & 7;
      float ssum = 0.f;
      for (int w3 = w2 + 1; w3 < NW; ++w3) ssum += totF[w3][r];
      suffD[w2][r] = carryD[par][r] + (double)ssum;
      if (w2 == 0) carryD[par ^ 1][r] = carryD[par][r] + (double)(ssum + totF[0][r]);
    }
    __syncthreads();
    par ^= 1;
    if ((jt << 10) > t0 + 7) continue;   // non-causal tile: scan contribution only

    float p[8];
    #pragma unroll
    for (int r = 0; r < 8; ++r) {
      double posd = suffD[w][r] + (double)locsuf[r];
      if (posd > 4351.0) posd = 4351.0;
      int idx = (int)posd;
      float wf = (float)(posd - (double)idx);
      int idx2 = idx < 4351 ? idx + 1 : 4351;
      float lf = li[r * T_ + idx];
      float lc = li[r * T_ + idx2];
      float bias = fmaf(wf, lc - lf, lf);
      const int t = t0 + r;
      const bool valid = sval && (s <= t) && !((t >= ST_ + SEQ_) && (s < ST_));
      float score = valid ? fmaf(lg[r], sc, bias) : -INFINITY;
      p[r] = __expf(score - mrow[r]);
      lsum[r] += p[r];
    }
    // PV: wave-private transpose, two half-s passes of 32
    const int sbase = (jt << 10) + (w << 6);
    if (sbase < T_) {
      #pragma unroll
      for (int pass = 0; pass < 2; ++pass) {
        if ((lane >> 5) == pass) {
          #pragma unroll
          for (int r = 0; r < 8; ++r) pbuf[w][r][lane & 31] = p[r];
        }
        const int s0 = sbase + (pass << 5);
        #pragma unroll 4
        for (int s4 = 0; s4 < 8; ++s4) {
          const int sb = s0 + (s4 << 2);
          float v0 = vb[(size_t)(sb + 0) * 64 + lane];
          float v1 = vb[(size_t)(sb + 1) * 64 + lane];
          float v2 = vb[(size_t)(sb + 2) * 64 + lane];
          float v3 = vb[(size_t)(sb + 3) * 64 + lane];
          #pragma unroll
          for (int r = 0; r < 8; ++r) {
            float4 pr = *reinterpret_cast<const float4*>(&pbuf[w][r][s4 << 2]);
            acc[r] = fmaf(pr.x, v0, fmaf(pr.y, v1, fmaf(pr.z, v2, fmaf(pr.w, v3, acc[r]))));
          }
        }
      }
    }
  }

  // ---- final merge across 16 waves ----
  #pragma unroll
  for (int r = 0; r < 8; ++r) {
    #pragma unroll
    for (int off = 32; off; off >>= 1) lsum[r] += __shfl_xor(lsum[r], off, 64);
  }
  if (lane == 0) {
    #pragma unroll
    for (int r = 0; r < 8; ++r) mlL[w][r] = lsum[r];
  }
  float* pb = &pbuf[w][0][0];
  #pragma unroll
  for (int pass = 0; pass < 2; ++pass) {
    __syncthreads();
    #pragma unroll
    for (int rr = 0; rr < 4; ++rr) pb[rr * 64 + lane] = acc[pass * 4 + rr];
    __syncthreads();
    if (tid < 256) {
      const int rr = tid >> 6, d = tid & 63;
      const int r = pass * 4 + rr;
      float o = 0.f, L = 0.f;
      #pragma unroll
      for (int w2 = 0; w2 < NW; ++w2) {
        o += (&pbuf[w2][0][0])[rr * 64 + d];
        L += mlL[w2][r];
      }
      out[((size_t)(b * T_ + t0 + r)) * 64 + d] = o / L;
    }
  }
}

extern "C" void kernel_launch(void* const* d_in, const int* in_sizes, int n_in,
                              void* d_out, int out_size, void* d_ws, size_t ws_size,
                              hipStream_t stream) {
  const float* x    = (const float*)d_in[0];
  const float* Wq   = (const float*)d_in[1];
  const float* Wk   = (const float*)d_in[2];
  const float* Wv   = (const float*)d_in[3];
  const float* Wqs  = (const float*)d_in[4];
  const float* Wks  = (const float*)d_in[5];
  const float* Wvs  = (const float*)d_in[6];
  const float* cope = (const float*)d_in[7];
  const float* scl  = (const float*)d_in[8];
  float* ws   = (float*)d_ws;
  float* outp = (float*)d_out;
  (void)in_sizes; (void)n_in; (void)out_size; (void)ws_size;

  hipLaunchKernelGGL(wtrans_kernel, dim3(16, 6), dim3(256), 0, stream,
                     Wq, Wk, Wv, Wqs, Wks, Wvs, ws);
  hipLaunchKernelGGL(proj_kernel, dim3(136, 2, 3), dim3(256), 0, stream, x, ws);
  hipLaunchKernelGGL(attn_kernel, dim3(544, 2), dim3(1024), 0, stream, ws, cope, scl, outp);
}

// Round 3
// 459.785 us; speedup vs baseline: 3.5476x; 1.5433x over previous
//
#include <hip/hip_runtime.h>
#include <math.h>

#define B_ 2
#define SEQ_ 4096
#define ST_ 128
#define T_ 4352
#define DIN_ 1024
#define NW 16
#define LMAX 3328

typedef _Float16 f16;
typedef __attribute__((ext_vector_type(8))) _Float16 f16x8;
typedef __attribute__((ext_vector_type(4))) float f32x4;

// ---- new-path ws byte offsets ----
#define OB_WT4 0
#define OB_QH  1572864
#define OB_QL  2686976
#define OB_KH  3801088
#define OB_KL  4915200
#define OB_VT  6029312
#define OB_CPT 7143424
#define OB_RMX 7569408
#define OB_LI  7604224
#define NEED_NEW 65538048ull

// ---- old-path ws float offsets ----
#define WT4_OFF 0
#define Q_OFF   393216
#define KT_OFF  950272
#define V_OFF   1507328

__device__ __forceinline__ int wuid() {
  return __builtin_amdgcn_readfirstlane((int)(threadIdx.x >> 6));
}

template<int CTRL, int RM>
__device__ __forceinline__ float dppadd(float x) {
  int y = __builtin_amdgcn_update_dpp(0, __float_as_int(x), CTRL, RM, 0xf, true);
  return x + __int_as_float(y);
}
// 64-lane inclusive scan (old path)
__device__ __forceinline__ float wave_iscan(float x) {
  x = dppadd<0x111, 0xf>(x);
  x = dppadd<0x112, 0xf>(x);
  x = dppadd<0x114, 0xf>(x);
  x = dppadd<0x118, 0xf>(x);
  x = dppadd<0x142, 0xa>(x);
  x = dppadd<0x143, 0xc>(x);
  return x;
}
// 16-lane inclusive scan (fragment rows)
__device__ __forceinline__ float p16scan(float x) {
  x = dppadd<0x111, 0xf>(x);
  x = dppadd<0x112, 0xf>(x);
  x = dppadd<0x114, 0xf>(x);
  x = dppadd<0x118, 0xf>(x);
  return x;
}
// broadcast lane15 of each 16-lane group
__device__ __forceinline__ float swz15(float x) {
  return __int_as_float(__builtin_amdgcn_ds_swizzle(__float_as_int(x), 0x1F0));
}

// ---------------- W -> WT4 permute (shared) ----------------
__global__ __launch_bounds__(256) void wtrans_kernel(
    const float* __restrict__ Wq,  const float* __restrict__ Wk,
    const float* __restrict__ Wv,  const float* __restrict__ Wqs,
    const float* __restrict__ Wks, const float* __restrict__ Wvs,
    float* __restrict__ ws) {
  const int m = blockIdx.y;
  const float* src = (m==0)?Wq:(m==1)?Wqs:(m==2)?Wk:(m==3)?Wks:(m==4)?Wv:Wvs;
  float* dst = ws + (size_t)m * (DIN_*64);
  const int bx = blockIdx.x;
  #pragma unroll
  for (int p = 0; p < 16; ++p) {
    int e = (int)threadIdx.x + (p << 8);
    int c = e & 3, o = (e >> 2) & 63;
    int i = (bx << 6) + (p << 2) + c;
    dst[(((bx << 4) + p) * 64 + o) * 4 + c] = src[o * DIN_ + i];
  }
}

// ---------------- cope transpose -> fp16 ----------------
__global__ __launch_bounds__(256) void copet_kernel(
    const float* __restrict__ cope, f16* __restrict__ copeT) {
  __shared__ float t2[64][65];
  const int l0 = blockIdx.x << 6;
  const int tid = (int)threadIdx.x;
  #pragma unroll
  for (int p = 0; p < 16; ++p) {
    int d = (p << 2) + (tid >> 6), c = tid & 63;
    t2[d][c] = cope[(size_t)d * T_ + l0 + c];
  }
  __syncthreads();
  #pragma unroll
  for (int p = 0; p < 16; ++p) {
    int l = (p << 2) + (tid >> 6), d = tid & 63;
    copeT[(size_t)(l0 + l) * 64 + d] = (f16)t2[d][l];
  }
}

// ---------------- new projections: fp16 split outputs ----------------
__global__ __launch_bounds__(256) void projB_kernel(
    const float* __restrict__ x, const float* __restrict__ wt4,
    f16* __restrict__ qh, f16* __restrict__ ql,
    f16* __restrict__ kh, f16* __restrict__ kl,
    f16* __restrict__ vt) {
  __shared__ float tile[32][65];
  const int t0 = blockIdx.x << 5;
  const int b  = blockIdx.y;
  const int pj = blockIdx.z;
  const int spec = (t0 < ST_ || t0 >= ST_ + SEQ_) ? 1 : 0;
  const float4* W4 = reinterpret_cast<const float4*>(wt4 + (size_t)(pj*2 + spec) * (DIN_*64));
  const int lane = (int)threadIdx.x & 63;
  const int w = wuid();
  const float* xb = x + ((size_t)(b * T_ + t0 + (w << 3))) * DIN_;
  float acc[8] = {0.f,0.f,0.f,0.f,0.f,0.f,0.f,0.f};
  #pragma unroll 4
  for (int i4 = 0; i4 < 256; ++i4) {
    float4 wv = W4[(i4 << 6) + lane];
    #pragma unroll
    for (int r = 0; r < 8; ++r) {
      float4 xv = reinterpret_cast<const float4*>(xb + r * DIN_)[i4];
      acc[r] = fmaf(wv.x, xv.x, fmaf(wv.y, xv.y, fmaf(wv.z, xv.z, fmaf(wv.w, xv.w, acc[r]))));
    }
  }
  float outv[8];
  #pragma unroll
  for (int r = 0; r < 8; ++r) {
    float sq = acc[r] * acc[r];
    #pragma unroll
    for (int off = 32; off; off >>= 1) sq += __shfl_xor(sq, off, 64);
    float n = fmaxf(sqrtf(sq), 1e-12f);
    outv[r] = acc[r] / n;
  }
  const int trow = t0 + (w << 3);
  if (pj == 2) {   // v -> vT fp16
    #pragma unroll
    for (int r = 0; r < 8; ++r) tile[(w << 3) + r][lane] = outv[r];
    __syncthreads();
    const int tid = (int)threadIdx.x;
    #pragma unroll
    for (int p = 0; p < 8; ++p) {
      int idx = tid + (p << 8);
      int d = idx >> 5, tt = idx & 31;
      vt[((size_t)(b * 64 + d)) * T_ + t0 + tt] = (f16)tile[tt][d];
    }
  } else {
    f16* hh = (pj == 0) ? qh : kh;
    f16* ll = (pj == 0) ? ql : kl;
    #pragma unroll
    for (int r = 0; r < 8; ++r) {
      size_t bt = (size_t)(b * T_ + trow + r) * 64 + lane;
      f16 h = (f16)outv[r];
      hh[bt] = h;
      ll[bt] = (f16)(outv[r] - (float)h);
    }
  }
}

// ---------------- li GEMM: li[b][t][l] fp16 + rowmax ----------------
__global__ __launch_bounds__(256) void li_kernel(
    const f16* __restrict__ qh, const f16* __restrict__ copeT,
    f16* __restrict__ li, float* __restrict__ rowmax) {
  __shared__ float rmx[4][16];
  const int tid = (int)threadIdx.x;
  const int lane = tid & 63;
  const int w = wuid();
  const int bt0 = (int)blockIdx.x << 4;
  const f16* qr = qh + (size_t)(bt0 + (lane & 15)) * 64 + ((lane >> 4) << 3);
  f16x8 aq0 = *reinterpret_cast<const f16x8*>(qr);
  f16x8 aq1 = *reinterpret_cast<const f16x8*>(qr + 32);
  float rm[4] = {-1e30f, -1e30f, -1e30f, -1e30f};
  for (int c = 0; c < 13; ++c) {
    const int lb = (c << 8) + (w << 6);
    #pragma unroll
    for (int nf = 0; nf < 4; ++nf) {
      const int lf = lb + (nf << 4);
      const f16* cr = copeT + (size_t)(lf + (lane & 15)) * 64 + ((lane >> 4) << 3);
      f16x8 b0 = *reinterpret_cast<const f16x8*>(cr);
      f16x8 b1 = *reinterpret_cast<const f16x8*>(cr + 32);
      f32x4 acc = {0.f, 0.f, 0.f, 0.f};
      acc = __builtin_amdgcn_mfma_f32_16x16x32_f16(aq0, b0, acc, 0, 0, 0);
      acc = __builtin_amdgcn_mfma_f32_16x16x32_f16(aq1, b1, acc, 0, 0, 0);
      #pragma unroll
      for (int reg = 0; reg < 4; ++reg) {
        f16 hv = (f16)acc[reg];
        int r = ((lane >> 4) << 2) + reg;
        li[(size_t)(bt0 + r) * LMAX + lf + (lane & 15)] = hv;
        rm[reg] = fmaxf(rm[reg], (float)hv);
      }
    }
  }
  #pragma unroll
  for (int reg = 0; reg < 4; ++reg) {
    #pragma unroll
    for (int k = 1; k < 16; k <<= 1) rm[reg] = fmaxf(rm[reg], __shfl_xor(rm[reg], k, 64));
  }
  if ((lane & 15) == 0) {
    #pragma unroll
    for (int reg = 0; reg < 4; ++reg) rmx[w][((lane >> 4) << 2) + reg] = rm[reg];
  }
  __syncthreads();
  if (tid < 16) {
    float m = fmaxf(fmaxf(rmx[0][tid], rmx[1][tid]), fmaxf(rmx[2][tid], rmx[3][tid]));
    rowmax[bt0 + tid] = m;
  }
}

// ---------------- fused attention (MFMA) ----------------
__global__ __launch_bounds__(1024) void attnB_kernel(
    const f16* __restrict__ qh, const f16* __restrict__ ql,
    const f16* __restrict__ kh, const f16* __restrict__ kl,
    const f16* __restrict__ vt, const f16* __restrict__ li,
    const float* __restrict__ rowmax, const float* __restrict__ scalep,
    float* __restrict__ out) {
  __shared__ __align__(16) unsigned char upool[36864];  // pstage [16w][16][72] f16  / obuf [4][8][64] f32x4
  __shared__ float totF[NW][16];
  __shared__ double suffD[NW][16];
  __shared__ double carryD[2][16];
  __shared__ float Lfin[16];

  const int tid = (int)threadIdx.x;
  const int lane = tid & 63;
  const int w = wuid();
  const int bt0 = ((int)(gridDim.x - 1 - blockIdx.x)) << 4;
  const int b = bt0 / T_;
  const int t0 = bt0 - b * T_;
  const float sc = scalep[0];
  const int qlo = lane & 15, qhi = lane >> 4;

  if (tid < 16) carryD[0][tid] = 0.0;

  // per-wave A-fragments of q (hi/lo)
  const f16* qrp = qh + (size_t)(bt0 + qlo) * 64 + (qhi << 3);
  const f16* qlp = ql + (size_t)(bt0 + qlo) * 64 + (qhi << 3);
  f16x8 aqh0 = *reinterpret_cast<const f16x8*>(qrp);
  f16x8 aqh1 = *reinterpret_cast<const f16x8*>(qrp + 32);
  f16x8 aql0 = *reinterpret_cast<const f16x8*>(qlp);
  f16x8 aql1 = *reinterpret_cast<const f16x8*>(qlp + 32);

  float mrw[4];
  #pragma unroll
  for (int reg = 0; reg < 4; ++reg)
    mrw[reg] = rowmax[bt0 + (qhi << 2) + reg] + fabsf(sc) + 2e-3f;

  f16* pst = reinterpret_cast<f16*>(upool) + w * (16 * 72);
  const size_t bT64 = (size_t)(b * T_) * 64;

  f32x4 oacc[4];
  #pragma unroll
  for (int nf = 0; nf < 4; ++nf) oacc[nf] = (f32x4){0.f, 0.f, 0.f, 0.f};
  float lsum[4] = {0.f, 0.f, 0.f, 0.f};
  int par = 0;

  for (int jt = 4; jt >= 0; --jt) {
    const int ts0 = jt << 10;
    const int swb = ts0 + (w << 6);
    // ---- QK^T (3-pass fp16 split) ----
    f32x4 sf[4];
    #pragma unroll
    for (int nf = 0; nf < 4; ++nf) {
      int sg = swb + (nf << 4) + qlo;
      int scl_ = sg < T_ ? sg : T_ - 1;
      const f16* krh = kh + bT64 + (size_t)scl_ * 64 + (qhi << 3);
      const f16* krl = kl + bT64 + (size_t)scl_ * 64 + (qhi << 3);
      f16x8 bh0 = *reinterpret_cast<const f16x8*>(krh);
      f16x8 bh1 = *reinterpret_cast<const f16x8*>(krh + 32);
      f16x8 bl0 = *reinterpret_cast<const f16x8*>(krl);
      f16x8 bl1 = *reinterpret_cast<const f16x8*>(krl + 32);
      f32x4 a = {0.f, 0.f, 0.f, 0.f};
      a = __builtin_amdgcn_mfma_f32_16x16x32_f16(aqh0, bh0, a, 0, 0, 0);
      a = __builtin_amdgcn_mfma_f32_16x16x32_f16(aqh1, bh1, a, 0, 0, 0);
      a = __builtin_amdgcn_mfma_f32_16x16x32_f16(aqh0, bl0, a, 0, 0, 0);
      a = __builtin_amdgcn_mfma_f32_16x16x32_f16(aqh1, bl1, a, 0, 0, 0);
      a = __builtin_amdgcn_mfma_f32_16x16x32_f16(aql0, bh0, a, 0, 0, 0);
      a = __builtin_amdgcn_mfma_f32_16x16x32_f16(aql1, bh1, a, 0, 0, 0);
      sf[nf] = a;
    }
    // ---- sigmoid + fragment-layout suffix scan ----
    float h_[4][4];
    float base[4] = {0.f, 0.f, 0.f, 0.f};
    #pragma unroll
    for (int nf = 0; nf < 4; ++nf) {
      int sg = swb + (nf << 4) + qlo;
      bool sval = sg < T_;
      #pragma unroll
      for (int reg = 0; reg < 4; ++reg) {
        float g = sval ? 1.f / (1.f + __expf(-sf[nf][reg])) : 0.f;
        float pf = p16scan(g);
        float tt = swz15(pf);
        h_[nf][reg] = g - pf - base[reg];
        base[reg] += tt;
      }
    }
    if ((lane & 15) == 0) {
      #pragma unroll
      for (int reg = 0; reg < 4; ++reg) totF[w][(qhi << 2) + reg] = base[reg];
    }
    __syncthreads();
    if (tid < 256) {
      const int w2 = tid >> 4, r = tid & 15;
      float ssum = 0.f;
      for (int w3 = w2 + 1; w3 < NW; ++w3) ssum += totF[w3][r];
      suffD[w2][r] = carryD[par][r] + (double)ssum;
      if (w2 == 0) carryD[par ^ 1][r] = carryD[par][r] + (double)(ssum + totF[0][r]);
    }
    __syncthreads();
    par ^= 1;
    if (ts0 > t0 + 15) continue;

    double sD[4];
    #pragma unroll
    for (int reg = 0; reg < 4; ++reg) sD[reg] = suffD[w][(qhi << 2) + reg];

    // ---- cope bias + p + stage P ----
    #pragma unroll
    for (int nf = 0; nf < 4; ++nf) {
      int sg = swb + (nf << 4) + qlo;
      #pragma unroll
      for (int reg = 0; reg < 4; ++reg) {
        int r = (qhi << 2) + reg;
        double posd = sD[reg] + (double)(base[reg] + h_[nf][reg]);
        posd = posd < 0.0 ? 0.0 : (posd > 3326.0 ? 3326.0 : posd);
        int idx = (int)posd;
        float wf = (float)(posd - (double)idx);
        const f16* lrow = li + (size_t)(bt0 + r) * LMAX + idx;
        float lf_ = (float)lrow[0], lc_ = (float)lrow[1];
        float bias = fmaf(wf, lc_ - lf_, lf_);
        int tl = t0 + r;
        bool valid = (sg <= tl) && !((tl >= ST_ + SEQ_) && (sg < ST_));
        float p = 0.f;
        if (valid) p = __expf(fmaf(sf[nf][reg], sc, bias) - mrw[reg]);
        lsum[reg] += p;
        int blk = ((nf << 1) + (qlo >> 3)) ^ (r & 7);
        pst[r * 72 + (blk << 3) + (lane & 7)] = (f16)p;
      }
    }
    // ---- PV MFMA ----
    {
      int m = qlo;
      const f16* pr = pst + m * 72;
      f16x8 pa0 = *reinterpret_cast<const f16x8*>(pr + (((qhi) ^ (m & 7)) << 3));
      f16x8 pa1 = *reinterpret_cast<const f16x8*>(pr + (((4 + qhi) ^ (m & 7)) << 3));
      int sv0 = swb + (qhi << 3);
      int sv1 = sv0 + 32;
      sv0 = sv0 < T_ - 8 ? sv0 : T_ - 8;
      sv1 = sv1 < T_ - 8 ? sv1 : T_ - 8;
      #pragma unroll
      for (int nf = 0; nf < 4; ++nf) {
        int d = (nf << 4) + qlo;
        const f16* vr = vt + (size_t)(b * 64 + d) * T_;
        f16x8 vb0 = *reinterpret_cast<const f16x8*>(vr + sv0);
        f16x8 vb1 = *reinterpret_cast<const f16x8*>(vr + sv1);
        oacc[nf] = __builtin_amdgcn_mfma_f32_16x16x32_f16(pa0, vb0, oacc[nf], 0, 0, 0);
        oacc[nf] = __builtin_amdgcn_mfma_f32_16x16x32_f16(pa1, vb1, oacc[nf], 0, 0, 0);
      }
    }
  }

  // ---- merge: lsum across waves ----
  #pragma unroll
  for (int reg = 0; reg < 4; ++reg) {
    #pragma unroll
    for (int k = 1; k < 16; k <<= 1) lsum[reg] += __shfl_xor(lsum[reg], k, 64);
  }
  if ((lane & 15) == 0) {
    #pragma unroll
    for (int reg = 0; reg < 4; ++reg) totF[w][(qhi << 2) + reg] = lsum[reg];
  }
  __syncthreads();   // pstage dead; totF holds per-wave L
  if (tid < 16) {
    float s = 0.f;
    for (int w2 = 0; w2 < NW; ++w2) s += totF[w2][tid];
    Lfin[tid] = s;
  }
  // ---- tree-reduce O across waves in upool ----
  f32x4* ob = reinterpret_cast<f32x4*>(upool);
  for (int half = 8; half >= 1; half >>= 1) {
    if (w >= half && w < 2 * half) {
      #pragma unroll
      for (int nf = 0; nf < 4; ++nf) ob[((nf << 3) + (w - half)) * 64 + lane] = oacc[nf];
    }
    __syncthreads();
    if (w < half) {
      #pragma unroll
      for (int nf = 0; nf < 4; ++nf) {
        f32x4 t = ob[((nf << 3) + w) * 64 + lane];
        #pragma unroll
        for (int reg = 0; reg < 4; ++reg) oacc[nf][reg] += t[reg];
      }
    }
    __syncthreads();
  }
  if (w == 0) {
    #pragma unroll
    for (int nf = 0; nf < 4; ++nf) {
      #pragma unroll
      for (int reg = 0; reg < 4; ++reg) {
        int r = (qhi << 2) + reg;
        out[(size_t)(bt0 + r) * 64 + (nf << 4) + qlo] = oacc[nf][reg] / Lfin[r];
      }
    }
  }
}

// =================== OLD PATH (fallback, proven) ===================
__global__ __launch_bounds__(256) void proj_kernel(
    const float* __restrict__ x, float* __restrict__ ws) {
  __shared__ float tile[32][65];
  const int t0 = blockIdx.x << 5;
  const int b  = blockIdx.y;
  const int pj = blockIdx.z;
  const int spec = (t0 < ST_ || t0 >= ST_ + SEQ_) ? 1 : 0;
  const float4* W4 = reinterpret_cast<const float4*>(ws + WT4_OFF + (size_t)(pj*2 + spec) * (DIN_*64));
  const int lane = (int)threadIdx.x & 63;
  const int w = wuid();
  const float* xb = x + ((size_t)(b * T_ + t0 + (w << 3))) * DIN_;
  float acc[8] = {0.f,0.f,0.f,0.f,0.f,0.f,0.f,0.f};
  #pragma unroll 4
  for (int i4 = 0; i4 < 256; ++i4) {
    float4 wv = W4[(i4 << 6) + lane];
    #pragma unroll
    for (int r = 0; r < 8; ++r) {
      float4 xv = reinterpret_cast<const float4*>(xb + r * DIN_)[i4];
      acc[r] = fmaf(wv.x, xv.x, fmaf(wv.y, xv.y, fmaf(wv.z, xv.z, fmaf(wv.w, xv.w, acc[r]))));
    }
  }
  float outv[8];
  #pragma unroll
  for (int r = 0; r < 8; ++r) {
    float sq = acc[r] * acc[r];
    #pragma unroll
    for (int off = 32; off; off >>= 1) sq += __shfl_xor(sq, off, 64);
    float n = fmaxf(sqrtf(sq), 1e-12f);
    outv[r] = acc[r] / n;
  }
  const int trow = t0 + (w << 3);
  if (pj != 1) {
    float* dst = ws + (pj == 0 ? Q_OFF : V_OFF) + ((size_t)(b * T_ + trow)) * 64;
    #pragma unroll
    for (int r = 0; r < 8; ++r) dst[r * 64 + lane] = outv[r];
  } else {
    #pragma unroll
    for (int r = 0; r < 8; ++r) tile[(w << 3) + r][lane] = outv[r];
    __syncthreads();
    float* kt = ws + KT_OFF + (size_t)b * 16 * T_ * 4;
    #pragma unroll
    for (int p = 0; p < 8; ++p) {
      int e = (int)threadIdx.x + (p << 8);
      int c = e & 3, tt = (e >> 2) & 31, d4 = e >> 7;
      kt[((size_t)d4 * T_ + t0 + tt) * 4 + c] = tile[tt][(d4 << 2) + c];
    }
  }
}

__global__ __launch_bounds__(1024) void attn_kernel(
    const float* __restrict__ ws_c, const float* __restrict__ cope,
    const float* __restrict__ scalep, float* __restrict__ out) {
  __shared__ float li_s[8 * T_];
  __shared__ float pbuf[NW][8][32];
  __shared__ float totF[NW][8];
  __shared__ double suffD[NW][8];
  __shared__ double carryD[2][8];
  __shared__ float mlL[NW][8];
  __shared__ float wmax[NW][8];
  const int tid = (int)threadIdx.x;
  const int lane = tid & 63;
  const int w = wuid();
  const int t0 = ((int)(gridDim.x - 1 - blockIdx.x)) << 3;
  const int b  = blockIdx.y;
  const float* qrow = ws_c + Q_OFF + ((size_t)(b * T_ + t0)) * 64;
  const float* ktb  = ws_c + KT_OFF + (size_t)b * 16 * T_ * 4;
  const float* vb   = ws_c + V_OFF + ((size_t)b * T_) * 64;
  const float sc = scalep[0];
  if (tid < 8) carryD[0][tid] = 0.0;
  float lm[8];
  #pragma unroll
  for (int r = 0; r < 8; ++r) lm[r] = -INFINITY;
  for (int jt = 0; jt < 5; ++jt) {
    const int l = (jt << 10) + tid;
    if (l < T_) {
      float a[8] = {0,0,0,0,0,0,0,0};
      #pragma unroll 4
      for (int d4 = 0; d4 < 16; ++d4) {
        float c0 = cope[(d4 * 4 + 0) * T_ + l];
        float c1 = cope[(d4 * 4 + 1) * T_ + l];
        float c2 = cope[(d4 * 4 + 2) * T_ + l];
        float c3 = cope[(d4 * 4 + 3) * T_ + l];
        #pragma unroll
        for (int r = 0; r < 8; ++r) {
          float4 qq = *reinterpret_cast<const float4*>(qrow + r * 64 + (d4 << 2));
          a[r] = fmaf(c0, qq.x, fmaf(c1, qq.y, fmaf(c2, qq.z, fmaf(c3, qq.w, a[r]))));
        }
      }
      #pragma unroll
      for (int r = 0; r < 8; ++r) { li_s[r * T_ + l] = a[r]; lm[r] = fmaxf(lm[r], a[r]); }
    }
  }
  #pragma unroll
  for (int r = 0; r < 8; ++r) {
    #pragma unroll
    for (int off = 32; off; off >>= 1) lm[r] = fmaxf(lm[r], __shfl_xor(lm[r], off, 64));
  }
  if (lane == 0) {
    #pragma unroll
    for (int r = 0; r < 8; ++r) wmax[w][r] = lm[r];
  }
  __syncthreads();
  float mrow[8];
  #pragma unroll
  for (int r = 0; r < 8; ++r) {
    float mm = wmax[0][r];
    #pragma unroll
    for (int w2 = 1; w2 < NW; ++w2) mm = fmaxf(mm, wmax[w2][r]);
    mrow[r] = mm + fabsf(sc) + 1e-3f;
  }
  float acc[8]  = {0,0,0,0,0,0,0,0};
  float lsum[8] = {0,0,0,0,0,0,0,0};
  int par = 0;
  for (int jt = 4; jt >= 0; --jt) {
    const int s = (jt << 10) + tid;
    const bool sval = (s < T_);
    float lg[8] = {0,0,0,0,0,0,0,0};
    if (sval) {
      #pragma unroll 4
      for (int d4 = 0; d4 < 16; ++d4) {
        float4 kk = *reinterpret_cast<const float4*>(ktb + ((size_t)d4 * T_ + s) * 4);
        #pragma unroll
        for (int r = 0; r < 8; ++r) {
          float4 qq = *reinterpret_cast<const float4*>(qrow + r * 64 + (d4 << 2));
          lg[r] = fmaf(kk.x, qq.x, fmaf(kk.y, qq.y, fmaf(kk.z, qq.z, fmaf(kk.w, qq.w, lg[r]))));
        }
      }
    }
    float locsuf[8], gtot[8];
    #pragma unroll
    for (int r = 0; r < 8; ++r) {
      float g = sval ? 1.f / (1.f + __expf(-lg[r])) : 0.f;
      float xx = wave_iscan(g);
      float tt = __shfl(xx, 63, 64);
      locsuf[r] = tt - xx + g;
      gtot[r] = tt;
    }
    if (lane == 0) {
      #pragma unroll
      for (int r = 0; r < 8; ++r) totF[w][r] = gtot[r];
    }
    __syncthreads();
    if (tid < 128) {
      const int w2 = tid >> 3, r = tid & 7;
      float ssum = 0.f;
      for (int w3 = w2 + 1; w3 < NW; ++w3) ssum += totF[w3][r];
      suffD[w2][r] = carryD[par][r] + (double)ssum;
      if (w2 == 0) carryD[par ^ 1][r] = carryD[par][r] + (double)(ssum + totF[0][r]);
    }
    __syncthreads();
    par ^= 1;
    if ((jt << 10) > t0 + 7) continue;
    float p[8];
    #pragma unroll
    for (int r = 0; r < 8; ++r) {
      double posd = suffD[w][r] + (double)locsuf[r];
      if (posd > 4351.0) posd = 4351.0;
      int idx = (int)posd;
      float wf = (float)(posd - (double)idx);
      int idx2 = idx < 4351 ? idx + 1 : 4351;
      float lf = li_s[r * T_ + idx];
      float lc = li_s[r * T_ + idx2];
      float bias = fmaf(wf, lc - lf, lf);
      const int t = t0 + r;
      const bool valid = sval && (s <= t) && !((t >= ST_ + SEQ_) && (s < ST_));
      float score = valid ? fmaf(lg[r], sc, bias) : -INFINITY;
      p[r] = __expf(score - mrow[r]);
      lsum[r] += p[r];
    }
    const int sbase = (jt << 10) + (w << 6);
    if (sbase < T_) {
      #pragma unroll
      for (int pass = 0; pass < 2; ++pass) {
        if ((lane >> 5) == pass) {
          #pragma unroll
          for (int r = 0; r < 8; ++r) pbuf[w][r][lane & 31] = p[r];
        }
        const int s0 = sbase + (pass << 5);
        #pragma unroll 4
        for (int s4 = 0; s4 < 8; ++s4) {
          const int sb = s0 + (s4 << 2);
          float v0 = vb[(size_t)(sb + 0) * 64 + lane];
          float v1 = vb[(size_t)(sb + 1) * 64 + lane];
          float v2 = vb[(size_t)(sb + 2) * 64 + lane];
          float v3 = vb[(size_t)(sb + 3) * 64 + lane];
          #pragma unroll
          for (int r = 0; r < 8; ++r) {
            float4 pr = *reinterpret_cast<const float4*>(&pbuf[w][r][s4 << 2]);
            acc[r] = fmaf(pr.x, v0, fmaf(pr.y, v1, fmaf(pr.z, v2, fmaf(pr.w, v3, acc[r]))));
          }
        }
      }
    }
  }
  #pragma unroll
  for (int r = 0; r < 8; ++r) {
    #pragma unroll
    for (int off = 32; off; off >>= 1) lsum[r] += __shfl_xor(lsum[r], off, 64);
  }
  if (lane == 0) {
    #pragma unroll
    for (int r = 0; r < 8; ++r) mlL[w][r] = lsum[r];
  }
  float* pb = &pbuf[w][0][0];
  #pragma unroll
  for (int pass = 0; pass < 2; ++pass) {
    __syncthreads();
    #pragma unroll
    for (int rr = 0; rr < 4; ++rr) pb[rr * 64 + lane] = acc[pass * 4 + rr];
    __syncthreads();
    if (tid < 256) {
      const int rr = tid >> 6, d = tid & 63;
      const int r = pass * 4 + rr;
      float o = 0.f, L = 0.f;
      #pragma unroll
      for (int w2 = 0; w2 < NW; ++w2) {
        o += (&pbuf[w2][0][0])[rr * 64 + d];
        L += mlL[w2][r];
      }
      out[((size_t)(b * T_ + t0 + r)) * 64 + d] = o / L;
    }
  }
}

extern "C" void kernel_launch(void* const* d_in, const int* in_sizes, int n_in,
                              void* d_out, int out_size, void* d_ws, size_t ws_size,
                              hipStream_t stream) {
  const float* x    = (const float*)d_in[0];
  const float* Wq   = (const float*)d_in[1];
  const float* Wk   = (const float*)d_in[2];
  const float* Wv   = (const float*)d_in[3];
  const float* Wqs  = (const float*)d_in[4];
  const float* Wks  = (const float*)d_in[5];
  const float* Wvs  = (const float*)d_in[6];
  const float* cope = (const float*)d_in[7];
  const float* scl  = (const float*)d_in[8];
  float* outp = (float*)d_out;
  (void)in_sizes; (void)n_in; (void)out_size;

  if (ws_size >= NEED_NEW) {
    unsigned char* wb = (unsigned char*)d_ws;
    float* wt4 = (float*)(wb + OB_WT4);
    f16* qh = (f16*)(wb + OB_QH);
    f16* ql = (f16*)(wb + OB_QL);
    f16* kh = (f16*)(wb + OB_KH);
    f16* kl = (f16*)(wb + OB_KL);
    f16* vt = (f16*)(wb + OB_VT);
    f16* cpt = (f16*)(wb + OB_CPT);
    float* rmx = (float*)(wb + OB_RMX);
    f16* lig = (f16*)(wb + OB_LI);
    hipLaunchKernelGGL(wtrans_kernel, dim3(16, 6), dim3(256), 0, stream,
                       Wq, Wk, Wv, Wqs, Wks, Wvs, wt4);
    hipLaunchKernelGGL(copet_kernel, dim3(52), dim3(256), 0, stream, cope, cpt);
    hipLaunchKernelGGL(projB_kernel, dim3(136, 2, 3), dim3(256), 0, stream,
                       x, wt4, qh, ql, kh, kl, vt);
    hipLaunchKernelGGL(li_kernel, dim3(544), dim3(256), 0, stream, qh, cpt, lig, rmx);
    hipLaunchKernelGGL(attnB_kernel, dim3(544), dim3(1024), 0, stream,
                       qh, ql, kh, kl, vt, lig, rmx, scl, outp);
  } else {
    float* ws = (float*)d_ws;
    hipLaunchKernelGGL(wtrans_kernel, dim3(16, 6), dim3(256), 0, stream,
                       Wq, Wk, Wv, Wqs, Wks, Wvs, ws);
    hipLaunchKernelGGL(proj_kernel, dim3(136, 2, 3), dim3(256), 0, stream, x, ws);
    hipLaunchKernelGGL(attn_kernel, dim3(544, 2), dim3(1024), 0, stream, ws, cope, scl, outp);
  }
}

// Round 4
// 450.389 us; speedup vs baseline: 3.6216x; 1.0209x over previous
//
#include <hip/hip_runtime.h>
#include <math.h>

#define B_ 2
#define SEQ_ 4096
#define ST_ 128
#define T_ 4352
#define DIN_ 1024
#define NW 16
#define LMAX 3328
#define LPAD 3336

typedef _Float16 f16;
typedef __attribute__((ext_vector_type(8))) _Float16 f16x8;
typedef __attribute__((ext_vector_type(4))) float f32x4;

// ---- new-path ws byte offsets ----
#define OB_WT4 0
#define OB_QH  1572864
#define OB_QL  2686976
#define OB_KH  3801088
#define OB_KL  4915200
#define OB_VT  6029312
#define OB_CPT 7143424
#define NEED_NEW 7569408ull

// ---- old-path ws float offsets ----
#define WT4_OFF 0
#define Q_OFF   393216
#define KT_OFF  950272
#define V_OFF   1507328

__device__ __forceinline__ int wuid() {
  return __builtin_amdgcn_readfirstlane((int)(threadIdx.x >> 6));
}

template<int CTRL, int RM>
__device__ __forceinline__ float dppadd(float x) {
  int y = __builtin_amdgcn_update_dpp(0, __float_as_int(x), CTRL, RM, 0xf, true);
  return x + __int_as_float(y);
}
// 64-lane inclusive scan (old path)
__device__ __forceinline__ float wave_iscan(float x) {
  x = dppadd<0x111, 0xf>(x);
  x = dppadd<0x112, 0xf>(x);
  x = dppadd<0x114, 0xf>(x);
  x = dppadd<0x118, 0xf>(x);
  x = dppadd<0x142, 0xa>(x);
  x = dppadd<0x143, 0xc>(x);
  return x;
}
// 16-lane inclusive scan (fragment rows)
__device__ __forceinline__ float p16scan(float x) {
  x = dppadd<0x111, 0xf>(x);
  x = dppadd<0x112, 0xf>(x);
  x = dppadd<0x114, 0xf>(x);
  x = dppadd<0x118, 0xf>(x);
  return x;
}
// broadcast lane15 of each 16-lane group
__device__ __forceinline__ float swz15(float x) {
  return __int_as_float(__builtin_amdgcn_ds_swizzle(__float_as_int(x), 0x1F0));
}

// ---------------- W -> WT4 permute (shared) ----------------
__global__ __launch_bounds__(256) void wtrans_kernel(
    const float* __restrict__ Wq,  const float* __restrict__ Wk,
    const float* __restrict__ Wv,  const float* __restrict__ Wqs,
    const float* __restrict__ Wks, const float* __restrict__ Wvs,
    float* __restrict__ ws) {
  const int m = blockIdx.y;
  const float* src = (m==0)?Wq:(m==1)?Wqs:(m==2)?Wk:(m==3)?Wks:(m==4)?Wv:Wvs;
  float* dst = ws + (size_t)m * (DIN_*64);
  const int bx = blockIdx.x;
  #pragma unroll
  for (int p = 0; p < 16; ++p) {
    int e = (int)threadIdx.x + (p << 8);
    int c = e & 3, o = (e >> 2) & 63;
    int i = (bx << 6) + (p << 2) + c;
    dst[(((bx << 4) + p) * 64 + o) * 4 + c] = src[o * DIN_ + i];
  }
}

// ---------------- cope transpose -> fp16 ----------------
__global__ __launch_bounds__(256) void copet_kernel(
    const float* __restrict__ cope, f16* __restrict__ copeT) {
  __shared__ float t2[64][65];
  const int l0 = blockIdx.x << 6;
  const int tid = (int)threadIdx.x;
  #pragma unroll
  for (int p = 0; p < 16; ++p) {
    int d = (p << 2) + (tid >> 6), c = tid & 63;
    t2[d][c] = cope[(size_t)d * T_ + l0 + c];
  }
  __syncthreads();
  #pragma unroll
  for (int p = 0; p < 16; ++p) {
    int l = (p << 2) + (tid >> 6), d = tid & 63;
    copeT[(size_t)(l0 + l) * 64 + d] = (f16)t2[d][l];
  }
}

// ---------------- projections: fp16 split outputs ----------------
__global__ __launch_bounds__(256) void projB_kernel(
    const float* __restrict__ x, const float* __restrict__ wt4,
    f16* __restrict__ qh, f16* __restrict__ ql,
    f16* __restrict__ kh, f16* __restrict__ kl,
    f16* __restrict__ vt) {
  __shared__ float tile[32][65];
  const int t0 = blockIdx.x << 5;
  const int b  = blockIdx.y;
  const int pj = blockIdx.z;
  const int spec = (t0 < ST_ || t0 >= ST_ + SEQ_) ? 1 : 0;
  const float4* W4 = reinterpret_cast<const float4*>(wt4 + (size_t)(pj*2 + spec) * (DIN_*64));
  const int lane = (int)threadIdx.x & 63;
  const int w = wuid();
  const float* xb = x + ((size_t)(b * T_ + t0 + (w << 3))) * DIN_;
  float acc[8] = {0.f,0.f,0.f,0.f,0.f,0.f,0.f,0.f};
  #pragma unroll 4
  for (int i4 = 0; i4 < 256; ++i4) {
    float4 wv = W4[(i4 << 6) + lane];
    #pragma unroll
    for (int r = 0; r < 8; ++r) {
      float4 xv = reinterpret_cast<const float4*>(xb + r * DIN_)[i4];
      acc[r] = fmaf(wv.x, xv.x, fmaf(wv.y, xv.y, fmaf(wv.z, xv.z, fmaf(wv.w, xv.w, acc[r]))));
    }
  }
  float outv[8];
  #pragma unroll
  for (int r = 0; r < 8; ++r) {
    float sq = acc[r] * acc[r];
    #pragma unroll
    for (int off = 32; off; off >>= 1) sq += __shfl_xor(sq, off, 64);
    float n = fmaxf(sqrtf(sq), 1e-12f);
    outv[r] = acc[r] / n;
  }
  const int trow = t0 + (w << 3);
  if (pj == 2) {
    #pragma unroll
    for (int r = 0; r < 8; ++r) tile[(w << 3) + r][lane] = outv[r];
    __syncthreads();
    const int tid = (int)threadIdx.x;
    #pragma unroll
    for (int p = 0; p < 8; ++p) {
      int idx = tid + (p << 8);
      int d = idx >> 5, tt = idx & 31;
      vt[((size_t)(b * 64 + d)) * T_ + t0 + tt] = (f16)tile[tt][d];
    }
  } else {
    f16* hh = (pj == 0) ? qh : kh;
    f16* ll = (pj == 0) ? ql : kl;
    #pragma unroll
    for (int r = 0; r < 8; ++r) {
      size_t bt = (size_t)(b * T_ + trow + r) * 64 + lane;
      f16 h = (f16)outv[r];
      hh[bt] = h;
      ll[bt] = (f16)(outv[r] - (float)h);
    }
  }
}

// ---------------- fused attention (MFMA + in-LDS li) ----------------
__global__ __launch_bounds__(1024, 4) void attnB_kernel(
    const f16* __restrict__ qh, const f16* __restrict__ ql,
    const f16* __restrict__ kh, const f16* __restrict__ kl,
    const f16* __restrict__ vt, const f16* __restrict__ cpt,
    const float* __restrict__ scalep, float* __restrict__ out) {
  __shared__ __align__(16) f16 liL[16 * LPAD];          // 106,752 B
  __shared__ __align__(16) unsigned char upool[36864];  // pstage
  __shared__ float totF[NW][16];
  __shared__ double suffD[NW][16];
  __shared__ double carryD[2][16];
  __shared__ float rmxS[NW][16];

  const int tid = (int)threadIdx.x;
  const int lane = tid & 63;
  const int w = wuid();
  const int bt0 = ((int)(gridDim.x - 1 - blockIdx.x)) << 4;
  const int b = bt0 / T_;
  const int t0 = bt0 - b * T_;
  const float sc = scalep[0];
  const int qlo = lane & 15, qhi = lane >> 4;

  if (tid < 16) carryD[0][tid] = 0.0;

  // q fragments (hi/lo)
  const f16* qrp = qh + (size_t)(bt0 + qlo) * 64 + (qhi << 3);
  const f16* qlp = ql + (size_t)(bt0 + qlo) * 64 + (qhi << 3);
  f16x8 aqh0 = *reinterpret_cast<const f16x8*>(qrp);
  f16x8 aqh1 = *reinterpret_cast<const f16x8*>(qrp + 32);
  f16x8 aql0 = *reinterpret_cast<const f16x8*>(qlp);
  f16x8 aql1 = *reinterpret_cast<const f16x8*>(qlp + 32);

  // ---- phase 1: li rows (q.copeT) via MFMA into LDS + rowmax ----
  {
    float rm[4] = {-1e30f, -1e30f, -1e30f, -1e30f};
    #pragma unroll 2
    for (int c = 0; c < 13; ++c) {
      const int lf = w * 208 + (c << 4);
      const f16* cr = cpt + (size_t)(lf + qlo) * 64 + (qhi << 3);
      f16x8 b0 = *reinterpret_cast<const f16x8*>(cr);
      f16x8 b1 = *reinterpret_cast<const f16x8*>(cr + 32);
      f32x4 a = {0.f, 0.f, 0.f, 0.f};
      a = __builtin_amdgcn_mfma_f32_16x16x32_f16(aqh0, b0, a, 0, 0, 0);
      a = __builtin_amdgcn_mfma_f32_16x16x32_f16(aqh1, b1, a, 0, 0, 0);
      #pragma unroll
      for (int reg = 0; reg < 4; ++reg) {
        f16 hv = (f16)a[reg];
        liL[((qhi << 2) + reg) * LPAD + lf + qlo] = hv;
        rm[reg] = fmaxf(rm[reg], (float)hv);
      }
    }
    #pragma unroll
    for (int reg = 0; reg < 4; ++reg) {
      #pragma unroll
      for (int k = 1; k < 16; k <<= 1) rm[reg] = fmaxf(rm[reg], __shfl_xor(rm[reg], k, 64));
    }
    if (qlo == 0) {
      #pragma unroll
      for (int reg = 0; reg < 4; ++reg) rmxS[w][(qhi << 2) + reg] = rm[reg];
    }
  }
  __syncthreads();
  float mrw[4];
  #pragma unroll
  for (int reg = 0; reg < 4; ++reg) {
    float mm = rmxS[0][(qhi << 2) + reg];
    #pragma unroll
    for (int w2 = 1; w2 < NW; ++w2) mm = fmaxf(mm, rmxS[w2][(qhi << 2) + reg]);
    mrw[reg] = mm + fabsf(sc) + 2e-3f;
  }

  f16* pst = reinterpret_cast<f16*>(upool) + w * (16 * 72);
  const size_t bT64 = (size_t)(b * T_) * 64;

  f32x4 oacc[4];
  #pragma unroll
  for (int nf = 0; nf < 4; ++nf) oacc[nf] = (f32x4){0.f, 0.f, 0.f, 0.f};
  float lsum[4] = {0.f, 0.f, 0.f, 0.f};
  int par = 0;

  // ---- phase 2: right-to-left sweep, s-tiles of 1024 ----
  for (int jt = 4; jt >= 0; --jt) {
    const int ts0 = jt << 10;
    const int swb = ts0 + (w << 6);
    // QK^T (3-pass fp16 split)
    f32x4 sf[4];
    #pragma unroll
    for (int nf = 0; nf < 4; ++nf) {
      int sg = swb + (nf << 4) + qlo;
      int scl_ = sg < T_ ? sg : T_ - 1;
      const f16* krh = kh + bT64 + (size_t)scl_ * 64 + (qhi << 3);
      const f16* krl = kl + bT64 + (size_t)scl_ * 64 + (qhi << 3);
      f16x8 bh0 = *reinterpret_cast<const f16x8*>(krh);
      f16x8 bh1 = *reinterpret_cast<const f16x8*>(krh + 32);
      f16x8 bl0 = *reinterpret_cast<const f16x8*>(krl);
      f16x8 bl1 = *reinterpret_cast<const f16x8*>(krl + 32);
      f32x4 a = {0.f, 0.f, 0.f, 0.f};
      a = __builtin_amdgcn_mfma_f32_16x16x32_f16(aqh0, bh0, a, 0, 0, 0);
      a = __builtin_amdgcn_mfma_f32_16x16x32_f16(aqh1, bh1, a, 0, 0, 0);
      a = __builtin_amdgcn_mfma_f32_16x16x32_f16(aqh0, bl0, a, 0, 0, 0);
      a = __builtin_amdgcn_mfma_f32_16x16x32_f16(aqh1, bl1, a, 0, 0, 0);
      a = __builtin_amdgcn_mfma_f32_16x16x32_f16(aql0, bh0, a, 0, 0, 0);
      a = __builtin_amdgcn_mfma_f32_16x16x32_f16(aql1, bh1, a, 0, 0, 0);
      sf[nf] = a;
    }
    // sigmoid + in-fragment suffix scan (nf descending, independent swizzles)
    float h_[4][4];
    float Sc[4] = {0.f, 0.f, 0.f, 0.f};
    #pragma unroll
    for (int nfd = 3; nfd >= 0; --nfd) {
      int sg = swb + (nfd << 4) + qlo;
      bool sval = sg < T_;
      #pragma unroll
      for (int reg = 0; reg < 4; ++reg) {
        float g = sval ? 1.f / (1.f + __expf(-sf[nfd][reg])) : 0.f;
        float pf = p16scan(g);
        float tt = swz15(pf);
        h_[nfd][reg] = Sc[reg] + tt - pf + g;   // suffix within wave-tile
        Sc[reg] += tt;
      }
    }
    if (qlo == 0) {
      #pragma unroll
      for (int reg = 0; reg < 4; ++reg) totF[w][(qhi << 2) + reg] = Sc[reg];
    }
    __syncthreads();
    if (tid < 256) {
      const int w2 = tid >> 4, r = tid & 15;
      float ssum = 0.f;
      for (int w3 = w2 + 1; w3 < NW; ++w3) ssum += totF[w3][r];
      suffD[w2][r] = carryD[par][r] + (double)ssum;
      if (w2 == 0) carryD[par ^ 1][r] = carryD[par][r] + (double)(ssum + totF[0][r]);
    }
    __syncthreads();
    par ^= 1;
    if (ts0 > t0 + 15) continue;

    double sD[4];
    #pragma unroll
    for (int reg = 0; reg < 4; ++reg) sD[reg] = suffD[w][(qhi << 2) + reg];

    // cope bias (LDS gather) + p + stage P
    #pragma unroll
    for (int nf = 0; nf < 4; ++nf) {
      int sg = swb + (nf << 4) + qlo;
      #pragma unroll
      for (int reg = 0; reg < 4; ++reg) {
        int r = (qhi << 2) + reg;
        double posd = sD[reg] + (double)h_[nf][reg];
        posd = posd < 0.0 ? 0.0 : (posd > 3326.0 ? 3326.0 : posd);
        int idx = (int)posd;
        float wf = (float)(posd - (double)idx);
        const f16* lrow = liL + r * LPAD + idx;
        float lf_ = (float)lrow[0], lc_ = (float)lrow[1];
        float bias = fmaf(wf, lc_ - lf_, lf_);
        int tl = t0 + r;
        bool valid = (sg <= tl) && !((tl >= ST_ + SEQ_) && (sg < ST_));
        float p = 0.f;
        if (valid) p = __expf(fmaf(sf[nf][reg], sc, bias) - mrw[reg]);
        lsum[reg] += p;
        int blk = ((nf << 1) + (qlo >> 3)) ^ (r & 7);
        pst[r * 72 + (blk << 3) + (lane & 7)] = (f16)p;
      }
    }
    // PV MFMA
    {
      int m = qlo;
      const f16* pr = pst + m * 72;
      f16x8 pa0 = *reinterpret_cast<const f16x8*>(pr + (((qhi) ^ (m & 7)) << 3));
      f16x8 pa1 = *reinterpret_cast<const f16x8*>(pr + (((4 + qhi) ^ (m & 7)) << 3));
      int sv0 = swb + (qhi << 3);
      int sv1 = sv0 + 32;
      sv0 = sv0 < T_ - 8 ? sv0 : T_ - 8;
      sv1 = sv1 < T_ - 8 ? sv1 : T_ - 8;
      #pragma unroll
      for (int nf = 0; nf < 4; ++nf) {
        int d = (nf << 4) + qlo;
        const f16* vr = vt + (size_t)(b * 64 + d) * T_;
        f16x8 vb0 = *reinterpret_cast<const f16x8*>(vr + sv0);
        f16x8 vb1 = *reinterpret_cast<const f16x8*>(vr + sv1);
        oacc[nf] = __builtin_amdgcn_mfma_f32_16x16x32_f16(pa0, vb0, oacc[nf], 0, 0, 0);
        oacc[nf] = __builtin_amdgcn_mfma_f32_16x16x32_f16(pa1, vb1, oacc[nf], 0, 0, 0);
      }
    }
  }

  // ---- final merge (liL region is free now) ----
  #pragma unroll
  for (int reg = 0; reg < 4; ++reg) {
    #pragma unroll
    for (int k = 1; k < 16; k <<= 1) lsum[reg] += __shfl_xor(lsum[reg], k, 64);
  }
  __syncthreads();   // everyone done with liL/totF
  if (qlo == 0) {
    #pragma unroll
    for (int reg = 0; reg < 4; ++reg) totF[w][(qhi << 2) + reg] = lsum[reg];
  }
  float* ob = reinterpret_cast<float*>(liL);   // [16w][16r][64d]
  #pragma unroll
  for (int nf = 0; nf < 4; ++nf) {
    #pragma unroll
    for (int reg = 0; reg < 4; ++reg)
      ob[w * 1024 + ((qhi << 2) + reg) * 64 + (nf << 4) + qlo] = oacc[nf][reg];
  }
  __syncthreads();
  {
    const int r = tid >> 6, d = tid & 63;
    float L = 0.f, o = 0.f;
    #pragma unroll
    for (int w2 = 0; w2 < NW; ++w2) {
      L += totF[w2][r];
      o += ob[w2 * 1024 + tid];
    }
    out[(size_t)(bt0 + r) * 64 + d] = o / L;
  }
}

// =================== OLD PATH (fallback, proven) ===================
__global__ __launch_bounds__(256) void proj_kernel(
    const float* __restrict__ x, float* __restrict__ ws) {
  __shared__ float tile[32][65];
  const int t0 = blockIdx.x << 5;
  const int b  = blockIdx.y;
  const int pj = blockIdx.z;
  const int spec = (t0 < ST_ || t0 >= ST_ + SEQ_) ? 1 : 0;
  const float4* W4 = reinterpret_cast<const float4*>(ws + WT4_OFF + (size_t)(pj*2 + spec) * (DIN_*64));
  const int lane = (int)threadIdx.x & 63;
  const int w = wuid();
  const float* xb = x + ((size_t)(b * T_ + t0 + (w << 3))) * DIN_;
  float acc[8] = {0.f,0.f,0.f,0.f,0.f,0.f,0.f,0.f};
  #pragma unroll 4
  for (int i4 = 0; i4 < 256; ++i4) {
    float4 wv = W4[(i4 << 6) + lane];
    #pragma unroll
    for (int r = 0; r < 8; ++r) {
      float4 xv = reinterpret_cast<const float4*>(xb + r * DIN_)[i4];
      acc[r] = fmaf(wv.x, xv.x, fmaf(wv.y, xv.y, fmaf(wv.z, xv.z, fmaf(wv.w, xv.w, acc[r]))));
    }
  }
  float outv[8];
  #pragma unroll
  for (int r = 0; r < 8; ++r) {
    float sq = acc[r] * acc[r];
    #pragma unroll
    for (int off = 32; off; off >>= 1) sq += __shfl_xor(sq, off, 64);
    float n = fmaxf(sqrtf(sq), 1e-12f);
    outv[r] = acc[r] / n;
  }
  const int trow = t0 + (w << 3);
  if (pj != 1) {
    float* dst = ws + (pj == 0 ? Q_OFF : V_OFF) + ((size_t)(b * T_ + trow)) * 64;
    #pragma unroll
    for (int r = 0; r < 8; ++r) dst[r * 64 + lane] = outv[r];
  } else {
    #pragma unroll
    for (int r = 0; r < 8; ++r) tile[(w << 3) + r][lane] = outv[r];
    __syncthreads();
    float* kt = ws + KT_OFF + (size_t)b * 16 * T_ * 4;
    #pragma unroll
    for (int p = 0; p < 8; ++p) {
      int e = (int)threadIdx.x + (p << 8);
      int c = e & 3, tt = (e >> 2) & 31, d4 = e >> 7;
      kt[((size_t)d4 * T_ + t0 + tt) * 4 + c] = tile[tt][(d4 << 2) + c];
    }
  }
}

__global__ __launch_bounds__(1024) void attn_kernel(
    const float* __restrict__ ws_c, const float* __restrict__ cope,
    const float* __restrict__ scalep, float* __restrict__ out) {
  __shared__ float li_s[8 * T_];
  __shared__ float pbuf[NW][8][32];
  __shared__ float totF[NW][8];
  __shared__ double suffD[NW][8];
  __shared__ double carryD[2][8];
  __shared__ float mlL[NW][8];
  __shared__ float wmax[NW][8];
  const int tid = (int)threadIdx.x;
  const int lane = tid & 63;
  const int w = wuid();
  const int t0 = ((int)(gridDim.x - 1 - blockIdx.x)) << 3;
  const int b  = blockIdx.y;
  const float* qrow = ws_c + Q_OFF + ((size_t)(b * T_ + t0)) * 64;
  const float* ktb  = ws_c + KT_OFF + (size_t)b * 16 * T_ * 4;
  const float* vb   = ws_c + V_OFF + ((size_t)b * T_) * 64;
  const float sc = scalep[0];
  if (tid < 8) carryD[0][tid] = 0.0;
  float lm[8];
  #pragma unroll
  for (int r = 0; r < 8; ++r) lm[r] = -INFINITY;
  for (int jt = 0; jt < 5; ++jt) {
    const int l = (jt << 10) + tid;
    if (l < T_) {
      float a[8] = {0,0,0,0,0,0,0,0};
      #pragma unroll 4
      for (int d4 = 0; d4 < 16; ++d4) {
        float c0 = cope[(d4 * 4 + 0) * T_ + l];
        float c1 = cope[(d4 * 4 + 1) * T_ + l];
        float c2 = cope[(d4 * 4 + 2) * T_ + l];
        float c3 = cope[(d4 * 4 + 3) * T_ + l];
        #pragma unroll
        for (int r = 0; r < 8; ++r) {
          float4 qq = *reinterpret_cast<const float4*>(qrow + r * 64 + (d4 << 2));
          a[r] = fmaf(c0, qq.x, fmaf(c1, qq.y, fmaf(c2, qq.z, fmaf(c3, qq.w, a[r]))));
        }
      }
      #pragma unroll
      for (int r = 0; r < 8; ++r) { li_s[r * T_ + l] = a[r]; lm[r] = fmaxf(lm[r], a[r]); }
    }
  }
  #pragma unroll
  for (int r = 0; r < 8; ++r) {
    #pragma unroll
    for (int off = 32; off; off >>= 1) lm[r] = fmaxf(lm[r], __shfl_xor(lm[r], off, 64));
  }
  if (lane == 0) {
    #pragma unroll
    for (int r = 0; r < 8; ++r) wmax[w][r] = lm[r];
  }
  __syncthreads();
  float mrow[8];
  #pragma unroll
  for (int r = 0; r < 8; ++r) {
    float mm = wmax[0][r];
    #pragma unroll
    for (int w2 = 1; w2 < NW; ++w2) mm = fmaxf(mm, wmax[w2][r]);
    mrow[r] = mm + fabsf(sc) + 1e-3f;
  }
  float acc[8]  = {0,0,0,0,0,0,0,0};
  float lsum[8] = {0,0,0,0,0,0,0,0};
  int par = 0;
  for (int jt = 4; jt >= 0; --jt) {
    const int s = (jt << 10) + tid;
    const bool sval = (s < T_);
    float lg[8] = {0,0,0,0,0,0,0,0};
    if (sval) {
      #pragma unroll 4
      for (int d4 = 0; d4 < 16; ++d4) {
        float4 kk = *reinterpret_cast<const float4*>(ktb + ((size_t)d4 * T_ + s) * 4);
        #pragma unroll
        for (int r = 0; r < 8; ++r) {
          float4 qq = *reinterpret_cast<const float4*>(qrow + r * 64 + (d4 << 2));
          lg[r] = fmaf(kk.x, qq.x, fmaf(kk.y, qq.y, fmaf(kk.z, qq.z, fmaf(kk.w, qq.w, lg[r]))));
        }
      }
    }
    float locsuf[8], gtot[8];
    #pragma unroll
    for (int r = 0; r < 8; ++r) {
      float g = sval ? 1.f / (1.f + __expf(-lg[r])) : 0.f;
      float xx = wave_iscan(g);
      float tt = __shfl(xx, 63, 64);
      locsuf[r] = tt - xx + g;
      gtot[r] = tt;
    }
    if (lane == 0) {
      #pragma unroll
      for (int r = 0; r < 8; ++r) totF[w][r] = gtot[r];
    }
    __syncthreads();
    if (tid < 128) {
      const int w2 = tid >> 3, r = tid & 7;
      float ssum = 0.f;
      for (int w3 = w2 + 1; w3 < NW; ++w3) ssum += totF[w3][r];
      suffD[w2][r] = carryD[par][r] + (double)ssum;
      if (w2 == 0) carryD[par ^ 1][r] = carryD[par][r] + (double)(ssum + totF[0][r]);
    }
    __syncthreads();
    par ^= 1;
    if ((jt << 10) > t0 + 7) continue;
    float p[8];
    #pragma unroll
    for (int r = 0; r < 8; ++r) {
      double posd = suffD[w][r] + (double)locsuf[r];
      if (posd > 4351.0) posd = 4351.0;
      int idx = (int)posd;
      float wf = (float)(posd - (double)idx);
      int idx2 = idx < 4351 ? idx + 1 : 4351;
      float lf = li_s[r * T_ + idx];
      float lc = li_s[r * T_ + idx2];
      float bias = fmaf(wf, lc - lf, lf);
      const int t = t0 + r;
      const bool valid = sval && (s <= t) && !((t >= ST_ + SEQ_) && (s < ST_));
      float score = valid ? fmaf(lg[r], sc, bias) : -INFINITY;
      p[r] = __expf(score - mrow[r]);
      lsum[r] += p[r];
    }
    const int sbase = (jt << 10) + (w << 6);
    if (sbase < T_) {
      #pragma unroll
      for (int pass = 0; pass < 2; ++pass) {
        if ((lane >> 5) == pass) {
          #pragma unroll
          for (int r = 0; r < 8; ++r) pbuf[w][r][lane & 31] = p[r];
        }
        const int s0 = sbase + (pass << 5);
        #pragma unroll 4
        for (int s4 = 0; s4 < 8; ++s4) {
          const int sb = s0 + (s4 << 2);
          float v0 = vb[(size_t)(sb + 0) * 64 + lane];
          float v1 = vb[(size_t)(sb + 1) * 64 + lane];
          float v2 = vb[(size_t)(sb + 2) * 64 + lane];
          float v3 = vb[(size_t)(sb + 3) * 64 + lane];
          #pragma unroll
          for (int r = 0; r < 8; ++r) {
            float4 pr = *reinterpret_cast<const float4*>(&pbuf[w][r][s4 << 2]);
            acc[r] = fmaf(pr.x, v0, fmaf(pr.y, v1, fmaf(pr.z, v2, fmaf(pr.w, v3, acc[r]))));
          }
        }
      }
    }
  }
  #pragma unroll
  for (int r = 0; r < 8; ++r) {
    #pragma unroll
    for (int off = 32; off; off >>= 1) lsum[r] += __shfl_xor(lsum[r], off, 64);
  }
  if (lane == 0) {
    #pragma unroll
    for (int r = 0; r < 8; ++r) mlL[w][r] = lsum[r];
  }
  float* pb = &pbuf[w][0][0];
  #pragma unroll
  for (int pass = 0; pass < 2; ++pass) {
    __syncthreads();
    #pragma unroll
    for (int rr = 0; rr < 4; ++rr) pb[rr * 64 + lane] = acc[pass * 4 + rr];
    __syncthreads();
    if (tid < 256) {
      const int rr = tid >> 6, d = tid & 63;
      const int r = pass * 4 + rr;
      float o = 0.f, L = 0.f;
      #pragma unroll
      for (int w2 = 0; w2 < NW; ++w2) {
        o += (&pbuf[w2][0][0])[rr * 64 + d];
        L += mlL[w2][r];
      }
      out[((size_t)(b * T_ + t0 + r)) * 64 + d] = o / L;
    }
  }
}

extern "C" void kernel_launch(void* const* d_in, const int* in_sizes, int n_in,
                              void* d_out, int out_size, void* d_ws, size_t ws_size,
                              hipStream_t stream) {
  const float* x    = (const float*)d_in[0];
  const float* Wq   = (const float*)d_in[1];
  const float* Wk   = (const float*)d_in[2];
  const float* Wv   = (const float*)d_in[3];
  const float* Wqs  = (const float*)d_in[4];
  const float* Wks  = (const float*)d_in[5];
  const float* Wvs  = (const float*)d_in[6];
  const float* cope = (const float*)d_in[7];
  const float* scl  = (const float*)d_in[8];
  float* outp = (float*)d_out;
  (void)in_sizes; (void)n_in; (void)out_size;

  if (ws_size >= NEED_NEW) {
    unsigned char* wb = (unsigned char*)d_ws;
    float* wt4 = (float*)(wb + OB_WT4);
    f16* qh = (f16*)(wb + OB_QH);
    f16* ql = (f16*)(wb + OB_QL);
    f16* kh = (f16*)(wb + OB_KH);
    f16* kl = (f16*)(wb + OB_KL);
    f16* vt = (f16*)(wb + OB_VT);
    f16* cpt = (f16*)(wb + OB_CPT);
    hipLaunchKernelGGL(wtrans_kernel, dim3(16, 6), dim3(256), 0, stream,
                       Wq, Wk, Wv, Wqs, Wks, Wvs, wt4);
    hipLaunchKernelGGL(copet_kernel, dim3(52), dim3(256), 0, stream, cope, cpt);
    hipLaunchKernelGGL(projB_kernel, dim3(136, 2, 3), dim3(256), 0, stream,
                       x, wt4, qh, ql, kh, kl, vt);
    hipLaunchKernelGGL(attnB_kernel, dim3(544), dim3(1024), 0, stream,
                       qh, ql, kh, kl, vt, cpt, scl, outp);
  } else {
    float* ws = (float*)d_ws;
    hipLaunchKernelGGL(wtrans_kernel, dim3(16, 6), dim3(256), 0, stream,
                       Wq, Wk, Wv, Wqs, Wks, Wvs, ws);
    hipLaunchKernelGGL(proj_kernel, dim3(136, 2, 3), dim3(256), 0, stream, x, ws);
    hipLaunchKernelGGL(attn_kernel, dim3(544, 2), dim3(1024), 0, stream, ws, cope, scl, outp);
  }
}

// Round 5
// 444.450 us; speedup vs baseline: 3.6700x; 1.0134x over previous
//
#include <hip/hip_runtime.h>
#include <math.h>

#define B_ 2
#define SEQ_ 4096
#define ST_ 128
#define T_ 4352
#define DIN_ 1024
#define NW 16
#define LMAX 3328
#define LPAD 3336

typedef _Float16 f16;
typedef __attribute__((ext_vector_type(8))) _Float16 f16x8;
typedef __attribute__((ext_vector_type(4))) float f32x4;

// ---- new-path ws byte offsets ----
#define OB_WT4 0
#define OB_QH  1572864
#define OB_QL  2686976
#define OB_KH  3801088
#define OB_KL  4915200
#define OB_VT  6029312
#define OB_CPT 7143424
#define NEED_NEW 7569408ull

// ---- old-path ws float offsets ----
#define WT4_OFF 0
#define Q_OFF   393216
#define KT_OFF  950272
#define V_OFF   1507328

__device__ __forceinline__ int wuid() {
  return __builtin_amdgcn_readfirstlane((int)(threadIdx.x >> 6));
}

template<int CTRL, int RM>
__device__ __forceinline__ float dppadd(float x) {
  int y = __builtin_amdgcn_update_dpp(0, __float_as_int(x), CTRL, RM, 0xf, true);
  return x + __int_as_float(y);
}
// 64-lane inclusive scan (old path)
__device__ __forceinline__ float wave_iscan(float x) {
  x = dppadd<0x111, 0xf>(x);
  x = dppadd<0x112, 0xf>(x);
  x = dppadd<0x114, 0xf>(x);
  x = dppadd<0x118, 0xf>(x);
  x = dppadd<0x142, 0xa>(x);
  x = dppadd<0x143, 0xc>(x);
  return x;
}
// 16-lane inclusive scan (fragment rows)
__device__ __forceinline__ float p16scan(float x) {
  x = dppadd<0x111, 0xf>(x);
  x = dppadd<0x112, 0xf>(x);
  x = dppadd<0x114, 0xf>(x);
  x = dppadd<0x118, 0xf>(x);
  return x;
}
// broadcast lane15 of each 16-lane group
__device__ __forceinline__ float swz15(float x) {
  return __int_as_float(__builtin_amdgcn_ds_swizzle(__float_as_int(x), 0x1F0));
}

// ---------------- W -> WT4 permute (shared) ----------------
__global__ __launch_bounds__(256) void wtrans_kernel(
    const float* __restrict__ Wq,  const float* __restrict__ Wk,
    const float* __restrict__ Wv,  const float* __restrict__ Wqs,
    const float* __restrict__ Wks, const float* __restrict__ Wvs,
    float* __restrict__ ws) {
  const int m = blockIdx.y;
  const float* src = (m==0)?Wq:(m==1)?Wqs:(m==2)?Wk:(m==3)?Wks:(m==4)?Wv:Wvs;
  float* dst = ws + (size_t)m * (DIN_*64);
  const int bx = blockIdx.x;
  #pragma unroll
  for (int p = 0; p < 16; ++p) {
    int e = (int)threadIdx.x + (p << 8);
    int c = e & 3, o = (e >> 2) & 63;
    int i = (bx << 6) + (p << 2) + c;
    dst[(((bx << 4) + p) * 64 + o) * 4 + c] = src[o * DIN_ + i];
  }
}

// ---------------- cope transpose -> fp16 ----------------
__global__ __launch_bounds__(256) void copet_kernel(
    const float* __restrict__ cope, f16* __restrict__ copeT) {
  __shared__ float t2[64][65];
  const int l0 = blockIdx.x << 6;
  const int tid = (int)threadIdx.x;
  #pragma unroll
  for (int p = 0; p < 16; ++p) {
    int d = (p << 2) + (tid >> 6), c = tid & 63;
    t2[d][c] = cope[(size_t)d * T_ + l0 + c];
  }
  __syncthreads();
  #pragma unroll
  for (int p = 0; p < 16; ++p) {
    int l = (p << 2) + (tid >> 6), d = tid & 63;
    copeT[(size_t)(l0 + l) * 64 + d] = (f16)t2[d][l];
  }
}

// ---------------- projections: fp16 split outputs ----------------
__global__ __launch_bounds__(256) void projB_kernel(
    const float* __restrict__ x, const float* __restrict__ wt4,
    f16* __restrict__ qh, f16* __restrict__ ql,
    f16* __restrict__ kh, f16* __restrict__ kl,
    f16* __restrict__ vt) {
  __shared__ float tile[32][65];
  const int t0 = blockIdx.x << 5;
  const int b  = blockIdx.y;
  const int pj = blockIdx.z;
  const int spec = (t0 < ST_ || t0 >= ST_ + SEQ_) ? 1 : 0;
  const float4* W4 = reinterpret_cast<const float4*>(wt4 + (size_t)(pj*2 + spec) * (DIN_*64));
  const int lane = (int)threadIdx.x & 63;
  const int w = wuid();
  const float* xb = x + ((size_t)(b * T_ + t0 + (w << 3))) * DIN_;
  float acc[8] = {0.f,0.f,0.f,0.f,0.f,0.f,0.f,0.f};
  #pragma unroll 4
  for (int i4 = 0; i4 < 256; ++i4) {
    float4 wv = W4[(i4 << 6) + lane];
    #pragma unroll
    for (int r = 0; r < 8; ++r) {
      float4 xv = reinterpret_cast<const float4*>(xb + r * DIN_)[i4];
      acc[r] = fmaf(wv.x, xv.x, fmaf(wv.y, xv.y, fmaf(wv.z, xv.z, fmaf(wv.w, xv.w, acc[r]))));
    }
  }
  float outv[8];
  #pragma unroll
  for (int r = 0; r < 8; ++r) {
    float sq = acc[r] * acc[r];
    #pragma unroll
    for (int off = 32; off; off >>= 1) sq += __shfl_xor(sq, off, 64);
    float n = fmaxf(sqrtf(sq), 1e-12f);
    outv[r] = acc[r] / n;
  }
  const int trow = t0 + (w << 3);
  if (pj == 2) {
    #pragma unroll
    for (int r = 0; r < 8; ++r) tile[(w << 3) + r][lane] = outv[r];
    __syncthreads();
    const int tid = (int)threadIdx.x;
    #pragma unroll
    for (int p = 0; p < 8; ++p) {
      int idx = tid + (p << 8);
      int d = idx >> 5, tt = idx & 31;
      vt[((size_t)(b * 64 + d)) * T_ + t0 + tt] = (f16)tile[tt][d];
    }
  } else {
    f16* hh = (pj == 0) ? qh : kh;
    f16* ll = (pj == 0) ? ql : kl;
    #pragma unroll
    for (int r = 0; r < 8; ++r) {
      size_t bt = (size_t)(b * T_ + trow + r) * 64 + lane;
      f16 h = (f16)outv[r];
      hh[bt] = h;
      ll[bt] = (f16)(outv[r] - (float)h);
    }
  }
}

// ======== fully de-arrayed fragment pipeline macros ========
#define QKF(SF, NF) { \
  int sg_ = swb + (NF << 4) + qlo; \
  int scl_ = sg_ < T_ ? sg_ : T_ - 1; \
  const f16* krh_ = kh + bT64 + (size_t)scl_ * 64 + (qhi << 3); \
  const f16* krl_ = kl + bT64 + (size_t)scl_ * 64 + (qhi << 3); \
  f16x8 bh0_ = *reinterpret_cast<const f16x8*>(krh_); \
  f16x8 bh1_ = *reinterpret_cast<const f16x8*>(krh_ + 32); \
  f16x8 bl0_ = *reinterpret_cast<const f16x8*>(krl_); \
  f16x8 bl1_ = *reinterpret_cast<const f16x8*>(krl_ + 32); \
  f32x4 a_ = {0.f, 0.f, 0.f, 0.f}; \
  a_ = __builtin_amdgcn_mfma_f32_16x16x32_f16(aqh0, bh0_, a_, 0, 0, 0); \
  a_ = __builtin_amdgcn_mfma_f32_16x16x32_f16(aqh1, bh1_, a_, 0, 0, 0); \
  a_ = __builtin_amdgcn_mfma_f32_16x16x32_f16(aqh0, bl0_, a_, 0, 0, 0); \
  a_ = __builtin_amdgcn_mfma_f32_16x16x32_f16(aqh1, bl1_, a_, 0, 0, 0); \
  a_ = __builtin_amdgcn_mfma_f32_16x16x32_f16(aql0, bh0_, a_, 0, 0, 0); \
  a_ = __builtin_amdgcn_mfma_f32_16x16x32_f16(aql1, bh1_, a_, 0, 0, 0); \
  SF = a_; }

#define SIG1(SF, H, RG) { \
  float g_ = sval_ ? 1.f / (1.f + __expf(-SF[RG])) : 0.f; \
  float pf_ = p16scan(g_); \
  float tt_ = swz15(pf_); \
  H[RG] = Sc[RG] + tt_ - pf_ + g_; \
  Sc[RG] += tt_; }

#define SCF(SF, H, NF) { \
  bool sval_ = (swb + (NF << 4) + qlo) < T_; \
  SIG1(SF, H, 0) SIG1(SF, H, 1) SIG1(SF, H, 2) SIG1(SF, H, 3) }

#define P1(SF, H, NF, RG, SD) { \
  double posd_ = SD + (double)H[RG]; \
  posd_ = posd_ < 0.0 ? 0.0 : (posd_ > 3326.0 ? 3326.0 : posd_); \
  int idx_ = (int)posd_; \
  float wf_ = (float)(posd_ - (double)idx_); \
  const f16* lrow_ = liL + ((qhi << 2) + RG) * LPAD + idx_; \
  float lf_ = (float)lrow_[0], lc_ = (float)lrow_[1]; \
  float bias_ = fmaf(wf_, lc_ - lf_, lf_); \
  int tl_ = t0 + (qhi << 2) + RG; \
  bool valid_ = (sg_ <= tl_) && !((tl_ >= ST_ + SEQ_) && (sg_ < ST_)); \
  float p_ = valid_ ? __expf(fmaf(SF[RG], sc, bias_) - mrw[RG]) : 0.f; \
  lsum[RG] += p_; \
  int blk_ = ((NF << 1) + (qlo >> 3)) ^ (((qhi << 2) + RG) & 7); \
  pst[((qhi << 2) + RG) * 72 + (blk_ << 3) + (lane & 7)] = (f16)p_; }

#define PBF(SF, H, NF) { \
  int sg_ = swb + (NF << 4) + qlo; \
  P1(SF, H, NF, 0, sd0) P1(SF, H, NF, 1, sd1) \
  P1(SF, H, NF, 2, sd2) P1(SF, H, NF, 3, sd3) }

#define PVF(OA, NF) { \
  int d_ = (NF << 4) + qlo; \
  const f16* vr_ = vt + (size_t)(b * 64 + d_) * T_; \
  f16x8 v0_ = *reinterpret_cast<const f16x8*>(vr_ + sv0); \
  f16x8 v1_ = *reinterpret_cast<const f16x8*>(vr_ + sv1); \
  OA = __builtin_amdgcn_mfma_f32_16x16x32_f16(pa0, v0_, OA, 0, 0, 0); \
  OA = __builtin_amdgcn_mfma_f32_16x16x32_f16(pa1, v1_, OA, 0, 0, 0); }

#define OST(OA, NF) { \
  ob[w * 1024 + ((qhi << 2) + 0) * 64 + (NF << 4) + qlo] = OA[0]; \
  ob[w * 1024 + ((qhi << 2) + 1) * 64 + (NF << 4) + qlo] = OA[1]; \
  ob[w * 1024 + ((qhi << 2) + 2) * 64 + (NF << 4) + qlo] = OA[2]; \
  ob[w * 1024 + ((qhi << 2) + 3) * 64 + (NF << 4) + qlo] = OA[3]; }

// ---------------- fused attention (MFMA + in-LDS li) ----------------
__global__ __launch_bounds__(1024)
__attribute__((amdgpu_waves_per_eu(4, 4)))
void attnB_kernel(
    const f16* __restrict__ qh, const f16* __restrict__ ql,
    const f16* __restrict__ kh, const f16* __restrict__ kl,
    const f16* __restrict__ vt, const f16* __restrict__ cpt,
    const float* __restrict__ scalep, float* __restrict__ out) {
  __shared__ __align__(16) f16 liL[16 * LPAD];          // 106,752 B
  __shared__ __align__(16) unsigned char upool[36864];  // pstage
  __shared__ float totF[NW][16];
  __shared__ double suffD[NW][16];
  __shared__ double carryD[2][16];
  __shared__ float rmxS[NW][16];

  const int tid = (int)threadIdx.x;
  const int lane = tid & 63;
  const int w = wuid();
  const int bt0 = ((int)(gridDim.x - 1 - blockIdx.x)) << 4;
  const int b = bt0 / T_;
  const int t0 = bt0 - b * T_;
  const float sc = scalep[0];
  const int qlo = lane & 15, qhi = lane >> 4;

  if (tid < 16) carryD[0][tid] = 0.0;

  // q fragments (hi/lo)
  const f16* qrp = qh + (size_t)(bt0 + qlo) * 64 + (qhi << 3);
  const f16* qlp = ql + (size_t)(bt0 + qlo) * 64 + (qhi << 3);
  f16x8 aqh0 = *reinterpret_cast<const f16x8*>(qrp);
  f16x8 aqh1 = *reinterpret_cast<const f16x8*>(qrp + 32);
  f16x8 aql0 = *reinterpret_cast<const f16x8*>(qlp);
  f16x8 aql1 = *reinterpret_cast<const f16x8*>(qlp + 32);

  // ---- phase 1: li rows (q.copeT) via MFMA into LDS + rowmax ----
  {
    f32x4 rm = {-1e30f, -1e30f, -1e30f, -1e30f};
    #pragma unroll 2
    for (int c = 0; c < 13; ++c) {
      const int lf = w * 208 + (c << 4);
      const f16* cr = cpt + (size_t)(lf + qlo) * 64 + (qhi << 3);
      f16x8 b0 = *reinterpret_cast<const f16x8*>(cr);
      f16x8 b1 = *reinterpret_cast<const f16x8*>(cr + 32);
      f32x4 a = {0.f, 0.f, 0.f, 0.f};
      a = __builtin_amdgcn_mfma_f32_16x16x32_f16(aqh0, b0, a, 0, 0, 0);
      a = __builtin_amdgcn_mfma_f32_16x16x32_f16(aqh1, b1, a, 0, 0, 0);
      f16 h0_ = (f16)a[0]; liL[((qhi << 2) + 0) * LPAD + lf + qlo] = h0_; rm[0] = fmaxf(rm[0], (float)h0_);
      f16 h1_ = (f16)a[1]; liL[((qhi << 2) + 1) * LPAD + lf + qlo] = h1_; rm[1] = fmaxf(rm[1], (float)h1_);
      f16 h2_ = (f16)a[2]; liL[((qhi << 2) + 2) * LPAD + lf + qlo] = h2_; rm[2] = fmaxf(rm[2], (float)h2_);
      f16 h3_ = (f16)a[3]; liL[((qhi << 2) + 3) * LPAD + lf + qlo] = h3_; rm[3] = fmaxf(rm[3], (float)h3_);
    }
    #pragma unroll
    for (int k = 1; k < 16; k <<= 1) {
      rm[0] = fmaxf(rm[0], __shfl_xor(rm[0], k, 64));
      rm[1] = fmaxf(rm[1], __shfl_xor(rm[1], k, 64));
      rm[2] = fmaxf(rm[2], __shfl_xor(rm[2], k, 64));
      rm[3] = fmaxf(rm[3], __shfl_xor(rm[3], k, 64));
    }
    if (qlo == 0) {
      rmxS[w][(qhi << 2) + 0] = rm[0];
      rmxS[w][(qhi << 2) + 1] = rm[1];
      rmxS[w][(qhi << 2) + 2] = rm[2];
      rmxS[w][(qhi << 2) + 3] = rm[3];
    }
  }
  __syncthreads();
  f32x4 mrw;
  #pragma unroll
  for (int reg = 0; reg < 4; ++reg) {
    float mm = rmxS[0][(qhi << 2) + reg];
    #pragma unroll
    for (int w2 = 1; w2 < NW; ++w2) mm = fmaxf(mm, rmxS[w2][(qhi << 2) + reg]);
    mrw[reg] = mm + fabsf(sc) + 2e-3f;
  }

  f16* pst = reinterpret_cast<f16*>(upool) + w * (16 * 72);
  const size_t bT64 = (size_t)(b * T_) * 64;

  f32x4 o0 = {0.f,0.f,0.f,0.f}, o1 = {0.f,0.f,0.f,0.f};
  f32x4 o2 = {0.f,0.f,0.f,0.f}, o3 = {0.f,0.f,0.f,0.f};
  f32x4 lsum = {0.f,0.f,0.f,0.f};
  int par = 0;

  // ---- phase 2: right-to-left sweep, s-tiles of 1024 ----
  for (int jt = 4; jt >= 0; --jt) {
    const int ts0 = jt << 10;
    const int swb = ts0 + (w << 6);
    // QK^T (3-pass fp16 split), 4 named fragments
    f32x4 sf0, sf1, sf2, sf3;
    QKF(sf0, 0) QKF(sf1, 1) QKF(sf2, 2) QKF(sf3, 3)
    // sigmoid + in-fragment suffix scan, nf descending
    f32x4 h0, h1, h2, h3;
    f32x4 Sc = {0.f, 0.f, 0.f, 0.f};
    SCF(sf3, h3, 3) SCF(sf2, h2, 2) SCF(sf1, h1, 1) SCF(sf0, h0, 0)
    if (qlo == 0) {
      totF[w][(qhi << 2) + 0] = Sc[0];
      totF[w][(qhi << 2) + 1] = Sc[1];
      totF[w][(qhi << 2) + 2] = Sc[2];
      totF[w][(qhi << 2) + 3] = Sc[3];
    }
    __syncthreads();
    if (tid < 256) {
      const int w2 = tid >> 4, r = tid & 15;
      float ssum = 0.f;
      for (int w3 = w2 + 1; w3 < NW; ++w3) ssum += totF[w3][r];
      suffD[w2][r] = carryD[par][r] + (double)ssum;
      if (w2 == 0) carryD[par ^ 1][r] = carryD[par][r] + (double)(ssum + totF[0][r]);
    }
    __syncthreads();
    par ^= 1;
    if (ts0 > t0 + 15) continue;

    double sd0 = suffD[w][(qhi << 2) + 0];
    double sd1 = suffD[w][(qhi << 2) + 1];
    double sd2 = suffD[w][(qhi << 2) + 2];
    double sd3 = suffD[w][(qhi << 2) + 3];

    // cope bias (LDS gather) + p + stage P
    PBF(sf0, h0, 0) PBF(sf1, h1, 1) PBF(sf2, h2, 2) PBF(sf3, h3, 3)

    // PV MFMA
    {
      const f16* pr = pst + qlo * 72;
      f16x8 pa0 = *reinterpret_cast<const f16x8*>(pr + (((qhi) ^ (qlo & 7)) << 3));
      f16x8 pa1 = *reinterpret_cast<const f16x8*>(pr + (((4 + qhi) ^ (qlo & 7)) << 3));
      int sv0 = swb + (qhi << 3);
      int sv1 = sv0 + 32;
      sv0 = sv0 < T_ - 8 ? sv0 : T_ - 8;
      sv1 = sv1 < T_ - 8 ? sv1 : T_ - 8;
      PVF(o0, 0) PVF(o1, 1) PVF(o2, 2) PVF(o3, 3)
    }
  }

  // ---- final merge (liL region is free now) ----
  #pragma unroll
  for (int k = 1; k < 16; k <<= 1) {
    lsum[0] += __shfl_xor(lsum[0], k, 64);
    lsum[1] += __shfl_xor(lsum[1], k, 64);
    lsum[2] += __shfl_xor(lsum[2], k, 64);
    lsum[3] += __shfl_xor(lsum[3], k, 64);
  }
  __syncthreads();   // everyone done with liL/totF
  if (qlo == 0) {
    totF[w][(qhi << 2) + 0] = lsum[0];
    totF[w][(qhi << 2) + 1] = lsum[1];
    totF[w][(qhi << 2) + 2] = lsum[2];
    totF[w][(qhi << 2) + 3] = lsum[3];
  }
  float* ob = reinterpret_cast<float*>(liL);   // [16w][16r][64d]
  OST(o0, 0) OST(o1, 1) OST(o2, 2) OST(o3, 3)
  __syncthreads();
  {
    const int r = tid >> 6, d = tid & 63;
    float L = 0.f, o = 0.f;
    #pragma unroll
    for (int w2 = 0; w2 < NW; ++w2) {
      L += totF[w2][r];
      o += ob[w2 * 1024 + tid];
    }
    out[(size_t)(bt0 + r) * 64 + d] = o / L;
  }
}

// =================== OLD PATH (fallback, proven) ===================
__global__ __launch_bounds__(256) void proj_kernel(
    const float* __restrict__ x, float* __restrict__ ws) {
  __shared__ float tile[32][65];
  const int t0 = blockIdx.x << 5;
  const int b  = blockIdx.y;
  const int pj = blockIdx.z;
  const int spec = (t0 < ST_ || t0 >= ST_ + SEQ_) ? 1 : 0;
  const float4* W4 = reinterpret_cast<const float4*>(ws + WT4_OFF + (size_t)(pj*2 + spec) * (DIN_*64));
  const int lane = (int)threadIdx.x & 63;
  const int w = wuid();
  const float* xb = x + ((size_t)(b * T_ + t0 + (w << 3))) * DIN_;
  float acc[8] = {0.f,0.f,0.f,0.f,0.f,0.f,0.f,0.f};
  #pragma unroll 4
  for (int i4 = 0; i4 < 256; ++i4) {
    float4 wv = W4[(i4 << 6) + lane];
    #pragma unroll
    for (int r = 0; r < 8; ++r) {
      float4 xv = reinterpret_cast<const float4*>(xb + r * DIN_)[i4];
      acc[r] = fmaf(wv.x, xv.x, fmaf(wv.y, xv.y, fmaf(wv.z, xv.z, fmaf(wv.w, xv.w, acc[r]))));
    }
  }
  float outv[8];
  #pragma unroll
  for (int r = 0; r < 8; ++r) {
    float sq = acc[r] * acc[r];
    #pragma unroll
    for (int off = 32; off; off >>= 1) sq += __shfl_xor(sq, off, 64);
    float n = fmaxf(sqrtf(sq), 1e-12f);
    outv[r] = acc[r] / n;
  }
  const int trow = t0 + (w << 3);
  if (pj != 1) {
    float* dst = ws + (pj == 0 ? Q_OFF : V_OFF) + ((size_t)(b * T_ + trow)) * 64;
    #pragma unroll
    for (int r = 0; r < 8; ++r) dst[r * 64 + lane] = outv[r];
  } else {
    #pragma unroll
    for (int r = 0; r < 8; ++r) tile[(w << 3) + r][lane] = outv[r];
    __syncthreads();
    float* kt = ws + KT_OFF + (size_t)b * 16 * T_ * 4;
    #pragma unroll
    for (int p = 0; p < 8; ++p) {
      int e = (int)threadIdx.x + (p << 8);
      int c = e & 3, tt = (e >> 2) & 31, d4 = e >> 7;
      kt[((size_t)d4 * T_ + t0 + tt) * 4 + c] = tile[tt][(d4 << 2) + c];
    }
  }
}

__global__ __launch_bounds__(1024) void attn_kernel(
    const float* __restrict__ ws_c, const float* __restrict__ cope,
    const float* __restrict__ scalep, float* __restrict__ out) {
  __shared__ float li_s[8 * T_];
  __shared__ float pbuf[NW][8][32];
  __shared__ float totF[NW][8];
  __shared__ double suffD[NW][8];
  __shared__ double carryD[2][8];
  __shared__ float mlL[NW][8];
  __shared__ float wmax[NW][8];
  const int tid = (int)threadIdx.x;
  const int lane = tid & 63;
  const int w = wuid();
  const int t0 = ((int)(gridDim.x - 1 - blockIdx.x)) << 3;
  const int b  = blockIdx.y;
  const float* qrow = ws_c + Q_OFF + ((size_t)(b * T_ + t0)) * 64;
  const float* ktb  = ws_c + KT_OFF + (size_t)b * 16 * T_ * 4;
  const float* vb   = ws_c + V_OFF + ((size_t)b * T_) * 64;
  const float sc = scalep[0];
  if (tid < 8) carryD[0][tid] = 0.0;
  float lm[8];
  #pragma unroll
  for (int r = 0; r < 8; ++r) lm[r] = -INFINITY;
  for (int jt = 0; jt < 5; ++jt) {
    const int l = (jt << 10) + tid;
    if (l < T_) {
      float a[8] = {0,0,0,0,0,0,0,0};
      #pragma unroll 4
      for (int d4 = 0; d4 < 16; ++d4) {
        float c0 = cope[(d4 * 4 + 0) * T_ + l];
        float c1 = cope[(d4 * 4 + 1) * T_ + l];
        float c2 = cope[(d4 * 4 + 2) * T_ + l];
        float c3 = cope[(d4 * 4 + 3) * T_ + l];
        #pragma unroll
        for (int r = 0; r < 8; ++r) {
          float4 qq = *reinterpret_cast<const float4*>(qrow + r * 64 + (d4 << 2));
          a[r] = fmaf(c0, qq.x, fmaf(c1, qq.y, fmaf(c2, qq.z, fmaf(c3, qq.w, a[r]))));
        }
      }
      #pragma unroll
      for (int r = 0; r < 8; ++r) { li_s[r * T_ + l] = a[r]; lm[r] = fmaxf(lm[r], a[r]); }
    }
  }
  #pragma unroll
  for (int r = 0; r < 8; ++r) {
    #pragma unroll
    for (int off = 32; off; off >>= 1) lm[r] = fmaxf(lm[r], __shfl_xor(lm[r], off, 64));
  }
  if (lane == 0) {
    #pragma unroll
    for (int r = 0; r < 8; ++r) wmax[w][r] = lm[r];
  }
  __syncthreads();
  float mrow[8];
  #pragma unroll
  for (int r = 0; r < 8; ++r) {
    float mm = wmax[0][r];
    #pragma unroll
    for (int w2 = 1; w2 < NW; ++w2) mm = fmaxf(mm, wmax[w2][r]);
    mrow[r] = mm + fabsf(sc) + 1e-3f;
  }
  float acc[8]  = {0,0,0,0,0,0,0,0};
  float lsum[8] = {0,0,0,0,0,0,0,0};
  int par = 0;
  for (int jt = 4; jt >= 0; --jt) {
    const int s = (jt << 10) + tid;
    const bool sval = (s < T_);
    float lg[8] = {0,0,0,0,0,0,0,0};
    if (sval) {
      #pragma unroll 4
      for (int d4 = 0; d4 < 16; ++d4) {
        float4 kk = *reinterpret_cast<const float4*>(ktb + ((size_t)d4 * T_ + s) * 4);
        #pragma unroll
        for (int r = 0; r < 8; ++r) {
          float4 qq = *reinterpret_cast<const float4*>(qrow + r * 64 + (d4 << 2));
          lg[r] = fmaf(kk.x, qq.x, fmaf(kk.y, qq.y, fmaf(kk.z, qq.z, fmaf(kk.w, qq.w, lg[r]))));
        }
      }
    }
    float locsuf[8], gtot[8];
    #pragma unroll
    for (int r = 0; r < 8; ++r) {
      float g = sval ? 1.f / (1.f + __expf(-lg[r])) : 0.f;
      float xx = wave_iscan(g);
      float tt = __shfl(xx, 63, 64);
      locsuf[r] = tt - xx + g;
      gtot[r] = tt;
    }
    if (lane == 0) {
      #pragma unroll
      for (int r = 0; r < 8; ++r) totF[w][r] = gtot[r];
    }
    __syncthreads();
    if (tid < 128) {
      const int w2 = tid >> 3, r = tid & 7;
      float ssum = 0.f;
      for (int w3 = w2 + 1; w3 < NW; ++w3) ssum += totF[w3][r];
      suffD[w2][r] = carryD[par][r] + (double)ssum;
      if (w2 == 0) carryD[par ^ 1][r] = carryD[par][r] + (double)(ssum + totF[0][r]);
    }
    __syncthreads();
    par ^= 1;
    if ((jt << 10) > t0 + 7) continue;
    float p[8];
    #pragma unroll
    for (int r = 0; r < 8; ++r) {
      double posd = suffD[w][r] + (double)locsuf[r];
      if (posd > 4351.0) posd = 4351.0;
      int idx = (int)posd;
      float wf = (float)(posd - (double)idx);
      int idx2 = idx < 4351 ? idx + 1 : 4351;
      float lf = li_s[r * T_ + idx];
      float lc = li_s[r * T_ + idx2];
      float bias = fmaf(wf, lc - lf, lf);
      const int t = t0 + r;
      const bool valid = sval && (s <= t) && !((t >= ST_ + SEQ_) && (s < ST_));
      float score = valid ? fmaf(lg[r], sc, bias) : -INFINITY;
      p[r] = __expf(score - mrow[r]);
      lsum[r] += p[r];
    }
    const int sbase = (jt << 10) + (w << 6);
    if (sbase < T_) {
      #pragma unroll
      for (int pass = 0; pass < 2; ++pass) {
        if ((lane >> 5) == pass) {
          #pragma unroll
          for (int r = 0; r < 8; ++r) pbuf[w][r][lane & 31] = p[r];
        }
        const int s0 = sbase + (pass << 5);
        #pragma unroll 4
        for (int s4 = 0; s4 < 8; ++s4) {
          const int sb = s0 + (s4 << 2);
          float v0 = vb[(size_t)(sb + 0) * 64 + lane];
          float v1 = vb[(size_t)(sb + 1) * 64 + lane];
          float v2 = vb[(size_t)(sb + 2) * 64 + lane];
          float v3 = vb[(size_t)(sb + 3) * 64 + lane];
          #pragma unroll
          for (int r = 0; r < 8; ++r) {
            float4 pr = *reinterpret_cast<const float4*>(&pbuf[w][r][s4 << 2]);
            acc[r] = fmaf(pr.x, v0, fmaf(pr.y, v1, fmaf(pr.z, v2, fmaf(pr.w, v3, acc[r]))));
          }
        }
      }
    }
  }
  #pragma unroll
  for (int r = 0; r < 8; ++r) {
    #pragma unroll
    for (int off = 32; off; off >>= 1) lsum[r] += __shfl_xor(lsum[r], off, 64);
  }
  if (lane == 0) {
    #pragma unroll
    for (int r = 0; r < 8; ++r) mlL[w][r] = lsum[r];
  }
  float* pb = &pbuf[w][0][0];
  #pragma unroll
  for (int pass = 0; pass < 2; ++pass) {
    __syncthreads();
    #pragma unroll
    for (int rr = 0; rr < 4; ++rr) pb[rr * 64 + lane] = acc[pass * 4 + rr];
    __syncthreads();
    if (tid < 256) {
      const int rr = tid >> 6, d = tid & 63;
      const int r = pass * 4 + rr;
      float o = 0.f, L = 0.f;
      #pragma unroll
      for (int w2 = 0; w2 < NW; ++w2) {
        o += (&pbuf[w2][0][0])[rr * 64 + d];
        L += mlL[w2][r];
      }
      out[((size_t)(b * T_ + t0 + r)) * 64 + d] = o / L;
    }
  }
}

extern "C" void kernel_launch(void* const* d_in, const int* in_sizes, int n_in,
                              void* d_out, int out_size, void* d_ws, size_t ws_size,
                              hipStream_t stream) {
  const float* x    = (const float*)d_in[0];
  const float* Wq   = (const float*)d_in[1];
  const float* Wk   = (const float*)d_in[2];
  const float* Wv   = (const float*)d_in[3];
  const float* Wqs  = (const float*)d_in[4];
  const float* Wks  = (const float*)d_in[5];
  const float* Wvs  = (const float*)d_in[6];
  const float* cope = (const float*)d_in[7];
  const float* scl  = (const float*)d_in[8];
  float* outp = (float*)d_out;
  (void)in_sizes; (void)n_in; (void)out_size;

  if (ws_size >= NEED_NEW) {
    unsigned char* wb = (unsigned char*)d_ws;
    float* wt4 = (float*)(wb + OB_WT4);
    f16* qh = (f16*)(wb + OB_QH);
    f16* ql = (f16*)(wb + OB_QL);
    f16* kh = (f16*)(wb + OB_KH);
    f16* kl = (f16*)(wb + OB_KL);
    f16* vt = (f16*)(wb + OB_VT);
    f16* cpt = (f16*)(wb + OB_CPT);
    hipLaunchKernelGGL(wtrans_kernel, dim3(16, 6), dim3(256), 0, stream,
                       Wq, Wk, Wv, Wqs, Wks, Wvs, wt4);
    hipLaunchKernelGGL(copet_kernel, dim3(52), dim3(256), 0, stream, cope, cpt);
    hipLaunchKernelGGL(projB_kernel, dim3(136, 2, 3), dim3(256), 0, stream,
                       x, wt4, qh, ql, kh, kl, vt);
    hipLaunchKernelGGL(attnB_kernel, dim3(544), dim3(1024), 0, stream,
                       qh, ql, kh, kl, vt, cpt, scl, outp);
  } else {
    float* ws = (float*)d_ws;
    hipLaunchKernelGGL(wtrans_kernel, dim3(16, 6), dim3(256), 0, stream,
                       Wq, Wk, Wv, Wqs, Wks, Wvs, ws);
    hipLaunchKernelGGL(proj_kernel, dim3(136, 2, 3), dim3(256), 0, stream, x, ws);
    hipLaunchKernelGGL(attn_kernel, dim3(544, 2), dim3(1024), 0, stream, ws, cope, scl, outp);
  }
}

// Round 6
// 363.241 us; speedup vs baseline: 4.4905x; 1.2236x over previous
//
#include <hip/hip_runtime.h>
#include <math.h>

#define B_ 2
#define SEQ_ 4096
#define ST_ 128
#define T_ 4352
#define DIN_ 1024
#define NW 16
#define LMAX 3328
#define LPAD 3336

typedef _Float16 f16;
typedef __attribute__((ext_vector_type(8))) _Float16 f16x8;
typedef __attribute__((ext_vector_type(4))) float f32x4;

// ---- new-path ws byte offsets ----
#define OB_WT4 0
#define OB_QH  1572864
#define OB_QL  2686976
#define OB_KH  3801088
#define OB_KL  4915200
#define OB_VT  6029312
#define OB_CPT 7143424
#define NEED_NEW 7569408ull

// ---- old-path ws float offsets ----
#define WT4_OFF 0
#define Q_OFF   393216
#define KT_OFF  950272
#define V_OFF   1507328

__device__ __forceinline__ int wuid() {
  return __builtin_amdgcn_readfirstlane((int)(threadIdx.x >> 6));
}

template<int CTRL, int RM>
__device__ __forceinline__ float dppadd(float x) {
  int y = __builtin_amdgcn_update_dpp(0, __float_as_int(x), CTRL, RM, 0xf, true);
  return x + __int_as_float(y);
}
// 64-lane inclusive scan (old path)
__device__ __forceinline__ float wave_iscan(float x) {
  x = dppadd<0x111, 0xf>(x);
  x = dppadd<0x112, 0xf>(x);
  x = dppadd<0x114, 0xf>(x);
  x = dppadd<0x118, 0xf>(x);
  x = dppadd<0x142, 0xa>(x);
  x = dppadd<0x143, 0xc>(x);
  return x;
}
// 16-lane inclusive scan (fragment rows)
__device__ __forceinline__ float p16scan(float x) {
  x = dppadd<0x111, 0xf>(x);
  x = dppadd<0x112, 0xf>(x);
  x = dppadd<0x114, 0xf>(x);
  x = dppadd<0x118, 0xf>(x);
  return x;
}
// broadcast lane15 of each 16-lane group
__device__ __forceinline__ float swz15(float x) {
  return __int_as_float(__builtin_amdgcn_ds_swizzle(__float_as_int(x), 0x1F0));
}

// ---------------- W -> WT4 permute (shared) ----------------
__global__ __launch_bounds__(256) void wtrans_kernel(
    const float* __restrict__ Wq,  const float* __restrict__ Wk,
    const float* __restrict__ Wv,  const float* __restrict__ Wqs,
    const float* __restrict__ Wks, const float* __restrict__ Wvs,
    float* __restrict__ ws) {
  const int m = blockIdx.y;
  const float* src = (m==0)?Wq:(m==1)?Wqs:(m==2)?Wk:(m==3)?Wks:(m==4)?Wv:Wvs;
  float* dst = ws + (size_t)m * (DIN_*64);
  const int bx = blockIdx.x;
  #pragma unroll
  for (int p = 0; p < 16; ++p) {
    int e = (int)threadIdx.x + (p << 8);
    int c = e & 3, o = (e >> 2) & 63;
    int i = (bx << 6) + (p << 2) + c;
    dst[(((bx << 4) + p) * 64 + o) * 4 + c] = src[o * DIN_ + i];
  }
}

// ---------------- cope transpose -> fp16 ----------------
__global__ __launch_bounds__(256) void copet_kernel(
    const float* __restrict__ cope, f16* __restrict__ copeT) {
  __shared__ float t2[64][65];
  const int l0 = blockIdx.x << 6;
  const int tid = (int)threadIdx.x;
  #pragma unroll
  for (int p = 0; p < 16; ++p) {
    int d = (p << 2) + (tid >> 6), c = tid & 63;
    t2[d][c] = cope[(size_t)d * T_ + l0 + c];
  }
  __syncthreads();
  #pragma unroll
  for (int p = 0; p < 16; ++p) {
    int l = (p << 2) + (tid >> 6), d = tid & 63;
    copeT[(size_t)(l0 + l) * 64 + d] = (f16)t2[d][l];
  }
}

// ---------------- projections: fp16 split outputs ----------------
__global__ __launch_bounds__(256) void projB_kernel(
    const float* __restrict__ x, const float* __restrict__ wt4,
    f16* __restrict__ qh, f16* __restrict__ ql,
    f16* __restrict__ kh, f16* __restrict__ kl,
    f16* __restrict__ vt) {
  __shared__ float tile[32][65];
  const int t0 = blockIdx.x << 5;
  const int b  = blockIdx.y;
  const int pj = blockIdx.z;
  const int spec = (t0 < ST_ || t0 >= ST_ + SEQ_) ? 1 : 0;
  const float4* W4 = reinterpret_cast<const float4*>(wt4 + (size_t)(pj*2 + spec) * (DIN_*64));
  const int lane = (int)threadIdx.x & 63;
  const int w = wuid();
  const float* xb = x + ((size_t)(b * T_ + t0 + (w << 3))) * DIN_;
  float acc[8] = {0.f,0.f,0.f,0.f,0.f,0.f,0.f,0.f};
  #pragma unroll 4
  for (int i4 = 0; i4 < 256; ++i4) {
    float4 wv = W4[(i4 << 6) + lane];
    #pragma unroll
    for (int r = 0; r < 8; ++r) {
      float4 xv = reinterpret_cast<const float4*>(xb + r * DIN_)[i4];
      acc[r] = fmaf(wv.x, xv.x, fmaf(wv.y, xv.y, fmaf(wv.z, xv.z, fmaf(wv.w, xv.w, acc[r]))));
    }
  }
  float outv[8];
  #pragma unroll
  for (int r = 0; r < 8; ++r) {
    float sq = acc[r] * acc[r];
    #pragma unroll
    for (int off = 32; off; off >>= 1) sq += __shfl_xor(sq, off, 64);
    float n = fmaxf(sqrtf(sq), 1e-12f);
    outv[r] = acc[r] / n;
  }
  const int trow = t0 + (w << 3);
  if (pj == 2) {
    #pragma unroll
    for (int r = 0; r < 8; ++r) tile[(w << 3) + r][lane] = outv[r];
    __syncthreads();
    const int tid = (int)threadIdx.x;
    #pragma unroll
    for (int p = 0; p < 8; ++p) {
      int idx = tid + (p << 8);
      int d = idx >> 5, tt = idx & 31;
      vt[((size_t)(b * 64 + d)) * T_ + t0 + tt] = (f16)tile[tt][d];
    }
  } else {
    f16* hh = (pj == 0) ? qh : kh;
    f16* ll = (pj == 0) ? ql : kl;
    #pragma unroll
    for (int r = 0; r < 8; ++r) {
      size_t bt = (size_t)(b * T_ + trow + r) * 64 + lane;
      f16 h = (f16)outv[r];
      hh[bt] = h;
      ll[bt] = (f16)(outv[r] - (float)h);
    }
  }
}

// ======== fragment pipeline macros (2 fragments / wave / tile) ========
#define QKF(SF, NF) { \
  int sg_ = swb + (NF << 4) + qlo; \
  int scl_ = sg_ < T_ ? sg_ : T_ - 1; \
  const f16* krh_ = kh + bT64 + (size_t)scl_ * 64 + (qhi << 3); \
  const f16* krl_ = kl + bT64 + (size_t)scl_ * 64 + (qhi << 3); \
  f16x8 bh0_ = *reinterpret_cast<const f16x8*>(krh_); \
  f16x8 bh1_ = *reinterpret_cast<const f16x8*>(krh_ + 32); \
  f16x8 bl0_ = *reinterpret_cast<const f16x8*>(krl_); \
  f16x8 bl1_ = *reinterpret_cast<const f16x8*>(krl_ + 32); \
  f32x4 a_ = {0.f, 0.f, 0.f, 0.f}; \
  a_ = __builtin_amdgcn_mfma_f32_16x16x32_f16(aqh0, bh0_, a_, 0, 0, 0); \
  a_ = __builtin_amdgcn_mfma_f32_16x16x32_f16(aqh1, bh1_, a_, 0, 0, 0); \
  a_ = __builtin_amdgcn_mfma_f32_16x16x32_f16(aqh0, bl0_, a_, 0, 0, 0); \
  a_ = __builtin_amdgcn_mfma_f32_16x16x32_f16(aqh1, bl1_, a_, 0, 0, 0); \
  a_ = __builtin_amdgcn_mfma_f32_16x16x32_f16(aql0, bh0_, a_, 0, 0, 0); \
  a_ = __builtin_amdgcn_mfma_f32_16x16x32_f16(aql1, bh1_, a_, 0, 0, 0); \
  SF = a_; }

#define SIG1(SF, H, RG) { \
  float g_ = sval_ ? 1.f / (1.f + __expf(-SF[RG])) : 0.f; \
  float pf_ = p16scan(g_); \
  float tt_ = swz15(pf_); \
  H[RG] = Sc[RG] + tt_ - pf_ + g_; \
  Sc[RG] += tt_; }

#define SCF(SF, H, NF) { \
  bool sval_ = (swb + (NF << 4) + qlo) < T_; \
  SIG1(SF, H, 0) SIG1(SF, H, 1) SIG1(SF, H, 2) SIG1(SF, H, 3) }

#define P1(SF, H, NF, RG, SD) { \
  double posd_ = SD + (double)H[RG]; \
  posd_ = posd_ < 0.0 ? 0.0 : (posd_ > 3326.0 ? 3326.0 : posd_); \
  int idx_ = (int)posd_; \
  float wf_ = (float)(posd_ - (double)idx_); \
  const f16* lrow_ = liL + ((qhi << 2) + RG) * LPAD + idx_; \
  float lf_ = (float)lrow_[0], lc_ = (float)lrow_[1]; \
  float bias_ = fmaf(wf_, lc_ - lf_, lf_); \
  int tl_ = t0 + (qhi << 2) + RG; \
  bool valid_ = (sg_ <= tl_) && !((tl_ >= ST_ + SEQ_) && (sg_ < ST_)); \
  float p_ = valid_ ? __expf(fmaf(SF[RG], sc, bias_) - mrw[RG]) : 0.f; \
  lsum[RG] += p_; \
  pst[((qhi << 2) + RG) * 40 + (NF << 4) + qlo] = (f16)p_; }

#define PBF(SF, H, NF) { \
  int sg_ = swb + (NF << 4) + qlo; \
  P1(SF, H, NF, 0, sd0) P1(SF, H, NF, 1, sd1) \
  P1(SF, H, NF, 2, sd2) P1(SF, H, NF, 3, sd3) }

#define PVF(OA, NF) { \
  int d_ = (NF << 4) + qlo; \
  const f16* vr_ = vt + (size_t)(b * 64 + d_) * T_; \
  f16x8 v0_ = *reinterpret_cast<const f16x8*>(vr_ + sv0); \
  OA = __builtin_amdgcn_mfma_f32_16x16x32_f16(pa0, v0_, OA, 0, 0, 0); }

#define OST(OA, NF) { \
  ob[w * 1024 + ((qhi << 2) + 0) * 64 + (NF << 4) + qlo] = OA[0]; \
  ob[w * 1024 + ((qhi << 2) + 1) * 64 + (NF << 4) + qlo] = OA[1]; \
  ob[w * 1024 + ((qhi << 2) + 2) * 64 + (NF << 4) + qlo] = OA[2]; \
  ob[w * 1024 + ((qhi << 2) + 3) * 64 + (NF << 4) + qlo] = OA[3]; }

// ---------------- fused attention (MFMA + in-LDS li, s-tile 512) ----------------
__global__ __launch_bounds__(1024, 4) void attnB_kernel(
    const f16* __restrict__ qh, const f16* __restrict__ ql,
    const f16* __restrict__ kh, const f16* __restrict__ kl,
    const f16* __restrict__ vt, const f16* __restrict__ cpt,
    const float* __restrict__ scalep, float* __restrict__ out) {
  __shared__ __align__(16) f16 liL[16 * LPAD];          // 106,752 B (reused as f32 O-merge)
  __shared__ __align__(16) f16 pstage[NW * 16 * 40];    // 20,480 B
  __shared__ float totF[NW][16];
  __shared__ double suffD[NW][16];
  __shared__ double carryD[2][16];
  __shared__ float rmxS[NW][16];

  const int tid = (int)threadIdx.x;
  const int lane = tid & 63;
  const int w = wuid();
  const int bt0 = ((int)(gridDim.x - 1 - blockIdx.x)) << 4;
  const int b = bt0 / T_;
  const int t0 = bt0 - b * T_;
  const float sc = scalep[0];
  const int qlo = lane & 15, qhi = lane >> 4;

  if (tid < 16) carryD[0][tid] = 0.0;

  // q fragments (hi/lo)
  const f16* qrp = qh + (size_t)(bt0 + qlo) * 64 + (qhi << 3);
  const f16* qlp = ql + (size_t)(bt0 + qlo) * 64 + (qhi << 3);
  f16x8 aqh0 = *reinterpret_cast<const f16x8*>(qrp);
  f16x8 aqh1 = *reinterpret_cast<const f16x8*>(qrp + 32);
  f16x8 aql0 = *reinterpret_cast<const f16x8*>(qlp);
  f16x8 aql1 = *reinterpret_cast<const f16x8*>(qlp + 32);

  // ---- phase 1: li rows (q.copeT) via MFMA into LDS + rowmax ----
  {
    f32x4 rm = {-1e30f, -1e30f, -1e30f, -1e30f};
    #pragma unroll 2
    for (int c = 0; c < 13; ++c) {
      const int lf = w * 208 + (c << 4);
      const f16* cr = cpt + (size_t)(lf + qlo) * 64 + (qhi << 3);
      f16x8 b0 = *reinterpret_cast<const f16x8*>(cr);
      f16x8 b1 = *reinterpret_cast<const f16x8*>(cr + 32);
      f32x4 a = {0.f, 0.f, 0.f, 0.f};
      a = __builtin_amdgcn_mfma_f32_16x16x32_f16(aqh0, b0, a, 0, 0, 0);
      a = __builtin_amdgcn_mfma_f32_16x16x32_f16(aqh1, b1, a, 0, 0, 0);
      f16 h0_ = (f16)a[0]; liL[((qhi << 2) + 0) * LPAD + lf + qlo] = h0_; rm[0] = fmaxf(rm[0], (float)h0_);
      f16 h1_ = (f16)a[1]; liL[((qhi << 2) + 1) * LPAD + lf + qlo] = h1_; rm[1] = fmaxf(rm[1], (float)h1_);
      f16 h2_ = (f16)a[2]; liL[((qhi << 2) + 2) * LPAD + lf + qlo] = h2_; rm[2] = fmaxf(rm[2], (float)h2_);
      f16 h3_ = (f16)a[3]; liL[((qhi << 2) + 3) * LPAD + lf + qlo] = h3_; rm[3] = fmaxf(rm[3], (float)h3_);
    }
    #pragma unroll
    for (int k = 1; k < 16; k <<= 1) {
      rm[0] = fmaxf(rm[0], __shfl_xor(rm[0], k, 64));
      rm[1] = fmaxf(rm[1], __shfl_xor(rm[1], k, 64));
      rm[2] = fmaxf(rm[2], __shfl_xor(rm[2], k, 64));
      rm[3] = fmaxf(rm[3], __shfl_xor(rm[3], k, 64));
    }
    if (qlo == 0) {
      rmxS[w][(qhi << 2) + 0] = rm[0];
      rmxS[w][(qhi << 2) + 1] = rm[1];
      rmxS[w][(qhi << 2) + 2] = rm[2];
      rmxS[w][(qhi << 2) + 3] = rm[3];
    }
  }
  __syncthreads();
  f32x4 mrw;
  #pragma unroll
  for (int reg = 0; reg < 4; ++reg) {
    float mm = rmxS[0][(qhi << 2) + reg];
    #pragma unroll
    for (int w2 = 1; w2 < NW; ++w2) mm = fmaxf(mm, rmxS[w2][(qhi << 2) + reg]);
    mrw[reg] = mm + fabsf(sc) + 2e-3f;
  }

  f16* pst = pstage + w * 640;
  const size_t bT64 = (size_t)(b * T_) * 64;

  f32x4 o0 = {0.f,0.f,0.f,0.f}, o1 = {0.f,0.f,0.f,0.f};
  f32x4 o2 = {0.f,0.f,0.f,0.f}, o3 = {0.f,0.f,0.f,0.f};
  f32x4 lsum = {0.f,0.f,0.f,0.f};
  int par = 0;

  // ---- phase 2: right-to-left sweep, s-tiles of 512, 9 tiles ----
  for (int jt = 8; jt >= 0; --jt) {
    const int ts0 = jt << 9;
    const int swb = ts0 + (w << 5);
    // QK^T (3-pass fp16 split), 2 named fragments
    f32x4 sf0, sf1;
    QKF(sf0, 0) QKF(sf1, 1)
    // sigmoid + in-fragment suffix scan, nf descending
    f32x4 h0, h1;
    f32x4 Sc = {0.f, 0.f, 0.f, 0.f};
    SCF(sf1, h1, 1) SCF(sf0, h0, 0)
    if (qlo == 0) {
      totF[w][(qhi << 2) + 0] = Sc[0];
      totF[w][(qhi << 2) + 1] = Sc[1];
      totF[w][(qhi << 2) + 2] = Sc[2];
      totF[w][(qhi << 2) + 3] = Sc[3];
    }
    __syncthreads();
    if (tid < 256) {
      const int w2 = tid >> 4, r = tid & 15;
      float ssum = 0.f;
      for (int w3 = w2 + 1; w3 < NW; ++w3) ssum += totF[w3][r];
      suffD[w2][r] = carryD[par][r] + (double)ssum;
      if (w2 == 0) carryD[par ^ 1][r] = carryD[par][r] + (double)(ssum + totF[0][r]);
    }
    __syncthreads();
    par ^= 1;
    if (ts0 > t0 + 15) continue;

    double sd0 = suffD[w][(qhi << 2) + 0];
    double sd1 = suffD[w][(qhi << 2) + 1];
    double sd2 = suffD[w][(qhi << 2) + 2];
    double sd3 = suffD[w][(qhi << 2) + 3];

    // cope bias (LDS gather) + p + stage P
    PBF(sf0, h0, 0) PBF(sf1, h1, 1)

    // PV MFMA (one K=32 MFMA per output d-fragment)
    {
      const f16* pr = pst + qlo * 40;
      f16x8 pa0 = *reinterpret_cast<const f16x8*>(pr + (qhi << 3));
      int sv0 = swb + (qhi << 3);
      sv0 = sv0 < T_ - 8 ? sv0 : T_ - 8;
      PVF(o0, 0) PVF(o1, 1) PVF(o2, 2) PVF(o3, 3)
    }
  }

  // ---- final merge (liL region is free now) ----
  #pragma unroll
  for (int k = 1; k < 16; k <<= 1) {
    lsum[0] += __shfl_xor(lsum[0], k, 64);
    lsum[1] += __shfl_xor(lsum[1], k, 64);
    lsum[2] += __shfl_xor(lsum[2], k, 64);
    lsum[3] += __shfl_xor(lsum[3], k, 64);
  }
  __syncthreads();   // everyone done with liL/totF
  if (qlo == 0) {
    totF[w][(qhi << 2) + 0] = lsum[0];
    totF[w][(qhi << 2) + 1] = lsum[1];
    totF[w][(qhi << 2) + 2] = lsum[2];
    totF[w][(qhi << 2) + 3] = lsum[3];
  }
  float* ob = reinterpret_cast<float*>(liL);   // [16w][16r][64d]
  OST(o0, 0) OST(o1, 1) OST(o2, 2) OST(o3, 3)
  __syncthreads();
  {
    const int r = tid >> 6, d = tid & 63;
    float L = 0.f, o = 0.f;
    #pragma unroll
    for (int w2 = 0; w2 < NW; ++w2) {
      L += totF[w2][r];
      o += ob[w2 * 1024 + tid];
    }
    out[(size_t)(bt0 + r) * 64 + d] = o / L;
  }
}

// =================== OLD PATH (fallback, proven) ===================
__global__ __launch_bounds__(256) void proj_kernel(
    const float* __restrict__ x, float* __restrict__ ws) {
  __shared__ float tile[32][65];
  const int t0 = blockIdx.x << 5;
  const int b  = blockIdx.y;
  const int pj = blockIdx.z;
  const int spec = (t0 < ST_ || t0 >= ST_ + SEQ_) ? 1 : 0;
  const float4* W4 = reinterpret_cast<const float4*>(ws + WT4_OFF + (size_t)(pj*2 + spec) * (DIN_*64));
  const int lane = (int)threadIdx.x & 63;
  const int w = wuid();
  const float* xb = x + ((size_t)(b * T_ + t0 + (w << 3))) * DIN_;
  float acc[8] = {0.f,0.f,0.f,0.f,0.f,0.f,0.f,0.f};
  #pragma unroll 4
  for (int i4 = 0; i4 < 256; ++i4) {
    float4 wv = W4[(i4 << 6) + lane];
    #pragma unroll
    for (int r = 0; r < 8; ++r) {
      float4 xv = reinterpret_cast<const float4*>(xb + r * DIN_)[i4];
      acc[r] = fmaf(wv.x, xv.x, fmaf(wv.y, xv.y, fmaf(wv.z, xv.z, fmaf(wv.w, xv.w, acc[r]))));
    }
  }
  float outv[8];
  #pragma unroll
  for (int r = 0; r < 8; ++r) {
    float sq = acc[r] * acc[r];
    #pragma unroll
    for (int off = 32; off; off >>= 1) sq += __shfl_xor(sq, off, 64);
    float n = fmaxf(sqrtf(sq), 1e-12f);
    outv[r] = acc[r] / n;
  }
  const int trow = t0 + (w << 3);
  if (pj != 1) {
    float* dst = ws + (pj == 0 ? Q_OFF : V_OFF) + ((size_t)(b * T_ + trow)) * 64;
    #pragma unroll
    for (int r = 0; r < 8; ++r) dst[r * 64 + lane] = outv[r];
  } else {
    #pragma unroll
    for (int r = 0; r < 8; ++r) tile[(w << 3) + r][lane] = outv[r];
    __syncthreads();
    float* kt = ws + KT_OFF + (size_t)b * 16 * T_ * 4;
    #pragma unroll
    for (int p = 0; p < 8; ++p) {
      int e = (int)threadIdx.x + (p << 8);
      int c = e & 3, tt = (e >> 2) & 31, d4 = e >> 7;
      kt[((size_t)d4 * T_ + t0 + tt) * 4 + c] = tile[tt][(d4 << 2) + c];
    }
  }
}

__global__ __launch_bounds__(1024) void attn_kernel(
    const float* __restrict__ ws_c, const float* __restrict__ cope,
    const float* __restrict__ scalep, float* __restrict__ out) {
  __shared__ float li_s[8 * T_];
  __shared__ float pbuf[NW][8][32];
  __shared__ float totF[NW][8];
  __shared__ double suffD[NW][8];
  __shared__ double carryD[2][8];
  __shared__ float mlL[NW][8];
  __shared__ float wmax[NW][8];
  const int tid = (int)threadIdx.x;
  const int lane = tid & 63;
  const int w = wuid();
  const int t0 = ((int)(gridDim.x - 1 - blockIdx.x)) << 3;
  const int b  = blockIdx.y;
  const float* qrow = ws_c + Q_OFF + ((size_t)(b * T_ + t0)) * 64;
  const float* ktb  = ws_c + KT_OFF + (size_t)b * 16 * T_ * 4;
  const float* vb   = ws_c + V_OFF + ((size_t)b * T_) * 64;
  const float sc = scalep[0];
  if (tid < 8) carryD[0][tid] = 0.0;
  float lm[8];
  #pragma unroll
  for (int r = 0; r < 8; ++r) lm[r] = -INFINITY;
  for (int jt = 0; jt < 5; ++jt) {
    const int l = (jt << 10) + tid;
    if (l < T_) {
      float a[8] = {0,0,0,0,0,0,0,0};
      #pragma unroll 4
      for (int d4 = 0; d4 < 16; ++d4) {
        float c0 = cope[(d4 * 4 + 0) * T_ + l];
        float c1 = cope[(d4 * 4 + 1) * T_ + l];
        float c2 = cope[(d4 * 4 + 2) * T_ + l];
        float c3 = cope[(d4 * 4 + 3) * T_ + l];
        #pragma unroll
        for (int r = 0; r < 8; ++r) {
          float4 qq = *reinterpret_cast<const float4*>(qrow + r * 64 + (d4 << 2));
          a[r] = fmaf(c0, qq.x, fmaf(c1, qq.y, fmaf(c2, qq.z, fmaf(c3, qq.w, a[r]))));
        }
      }
      #pragma unroll
      for (int r = 0; r < 8; ++r) { li_s[r * T_ + l] = a[r]; lm[r] = fmaxf(lm[r], a[r]); }
    }
  }
  #pragma unroll
  for (int r = 0; r < 8; ++r) {
    #pragma unroll
    for (int off = 32; off; off >>= 1) lm[r] = fmaxf(lm[r], __shfl_xor(lm[r], off, 64));
  }
  if (lane == 0) {
    #pragma unroll
    for (int r = 0; r < 8; ++r) wmax[w][r] = lm[r];
  }
  __syncthreads();
  float mrow[8];
  #pragma unroll
  for (int r = 0; r < 8; ++r) {
    float mm = wmax[0][r];
    #pragma unroll
    for (int w2 = 1; w2 < NW; ++w2) mm = fmaxf(mm, wmax[w2][r]);
    mrow[r] = mm + fabsf(sc) + 1e-3f;
  }
  float acc[8]  = {0,0,0,0,0,0,0,0};
  float lsum[8] = {0,0,0,0,0,0,0,0};
  int par = 0;
  for (int jt = 4; jt >= 0; --jt) {
    const int s = (jt << 10) + tid;
    const bool sval = (s < T_);
    float lg[8] = {0,0,0,0,0,0,0,0};
    if (sval) {
      #pragma unroll 4
      for (int d4 = 0; d4 < 16; ++d4) {
        float4 kk = *reinterpret_cast<const float4*>(ktb + ((size_t)d4 * T_ + s) * 4);
        #pragma unroll
        for (int r = 0; r < 8; ++r) {
          float4 qq = *reinterpret_cast<const float4*>(qrow + r * 64 + (d4 << 2));
          lg[r] = fmaf(kk.x, qq.x, fmaf(kk.y, qq.y, fmaf(kk.z, qq.z, fmaf(kk.w, qq.w, lg[r]))));
        }
      }
    }
    float locsuf[8], gtot[8];
    #pragma unroll
    for (int r = 0; r < 8; ++r) {
      float g = sval ? 1.f / (1.f + __expf(-lg[r])) : 0.f;
      float xx = wave_iscan(g);
      float tt = __shfl(xx, 63, 64);
      locsuf[r] = tt - xx + g;
      gtot[r] = tt;
    }
    if (lane == 0) {
      #pragma unroll
      for (int r = 0; r < 8; ++r) totF[w][r] = gtot[r];
    }
    __syncthreads();
    if (tid < 128) {
      const int w2 = tid >> 3, r = tid & 7;
      float ssum = 0.f;
      for (int w3 = w2 + 1; w3 < NW; ++w3) ssum += totF[w3][r];
      suffD[w2][r] = carryD[par][r] + (double)ssum;
      if (w2 == 0) carryD[par ^ 1][r] = carryD[par][r] + (double)(ssum + totF[0][r]);
    }
    __syncthreads();
    par ^= 1;
    if ((jt << 10) > t0 + 7) continue;
    float p[8];
    #pragma unroll
    for (int r = 0; r < 8; ++r) {
      double posd = suffD[w][r] + (double)locsuf[r];
      if (posd > 4351.0) posd = 4351.0;
      int idx = (int)posd;
      float wf = (float)(posd - (double)idx);
      int idx2 = idx < 4351 ? idx + 1 : 4351;
      float lf = li_s[r * T_ + idx];
      float lc = li_s[r * T_ + idx2];
      float bias = fmaf(wf, lc - lf, lf);
      const int t = t0 + r;
      const bool valid = sval && (s <= t) && !((t >= ST_ + SEQ_) && (s < ST_));
      float score = valid ? fmaf(lg[r], sc, bias) : -INFINITY;
      p[r] = __expf(score - mrow[r]);
      lsum[r] += p[r];
    }
    const int sbase = (jt << 10) + (w << 6);
    if (sbase < T_) {
      #pragma unroll
      for (int pass = 0; pass < 2; ++pass) {
        if ((lane >> 5) == pass) {
          #pragma unroll
          for (int r = 0; r < 8; ++r) pbuf[w][r][lane & 31] = p[r];
        }
        const int s0 = sbase + (pass << 5);
        #pragma unroll 4
        for (int s4 = 0; s4 < 8; ++s4) {
          const int sb = s0 + (s4 << 2);
          float v0 = vb[(size_t)(sb + 0) * 64 + lane];
          float v1 = vb[(size_t)(sb + 1) * 64 + lane];
          float v2 = vb[(size_t)(sb + 2) * 64 + lane];
          float v3 = vb[(size_t)(sb + 3) * 64 + lane];
          #pragma unroll
          for (int r = 0; r < 8; ++r) {
            float4 pr = *reinterpret_cast<const float4*>(&pbuf[w][r][s4 << 2]);
            acc[r] = fmaf(pr.x, v0, fmaf(pr.y, v1, fmaf(pr.z, v2, fmaf(pr.w, v3, acc[r]))));
          }
        }
      }
    }
  }
  #pragma unroll
  for (int r = 0; r < 8; ++r) {
    #pragma unroll
    for (int off = 32; off; off >>= 1) lsum[r] += __shfl_xor(lsum[r], off, 64);
  }
  if (lane == 0) {
    #pragma unroll
    for (int r = 0; r < 8; ++r) mlL[w][r] = lsum[r];
  }
  float* pb = &pbuf[w][0][0];
  #pragma unroll
  for (int pass = 0; pass < 2; ++pass) {
    __syncthreads();
    #pragma unroll
    for (int rr = 0; rr < 4; ++rr) pb[rr * 64 + lane] = acc[pass * 4 + rr];
    __syncthreads();
    if (tid < 256) {
      const int rr = tid >> 6, d = tid & 63;
      const int r = pass * 4 + rr;
      float o = 0.f, L = 0.f;
      #pragma unroll
      for (int w2 = 0; w2 < NW; ++w2) {
        o += (&pbuf[w2][0][0])[rr * 64 + d];
        L += mlL[w2][r];
      }
      out[((size_t)(b * T_ + t0 + r)) * 64 + d] = o / L;
    }
  }
}

extern "C" void kernel_launch(void* const* d_in, const int* in_sizes, int n_in,
                              void* d_out, int out_size, void* d_ws, size_t ws_size,
                              hipStream_t stream) {
  const float* x    = (const float*)d_in[0];
  const float* Wq   = (const float*)d_in[1];
  const float* Wk   = (const float*)d_in[2];
  const float* Wv   = (const float*)d_in[3];
  const float* Wqs  = (const float*)d_in[4];
  const float* Wks  = (const float*)d_in[5];
  const float* Wvs  = (const float*)d_in[6];
  const float* cope = (const float*)d_in[7];
  const float* scl  = (const float*)d_in[8];
  float* outp = (float*)d_out;
  (void)in_sizes; (void)n_in; (void)out_size;

  if (ws_size >= NEED_NEW) {
    unsigned char* wb = (unsigned char*)d_ws;
    float* wt4 = (float*)(wb + OB_WT4);
    f16* qh = (f16*)(wb + OB_QH);
    f16* ql = (f16*)(wb + OB_QL);
    f16* kh = (f16*)(wb + OB_KH);
    f16* kl = (f16*)(wb + OB_KL);
    f16* vt = (f16*)(wb + OB_VT);
    f16* cpt = (f16*)(wb + OB_CPT);
    hipLaunchKernelGGL(wtrans_kernel, dim3(16, 6), dim3(256), 0, stream,
                       Wq, Wk, Wv, Wqs, Wks, Wvs, wt4);
    hipLaunchKernelGGL(copet_kernel, dim3(52), dim3(256), 0, stream, cope, cpt);
    hipLaunchKernelGGL(projB_kernel, dim3(136, 2, 3), dim3(256), 0, stream,
                       x, wt4, qh, ql, kh, kl, vt);
    hipLaunchKernelGGL(attnB_kernel, dim3(544), dim3(1024), 0, stream,
                       qh, ql, kh, kl, vt, cpt, scl, outp);
  } else {
    float* ws = (float*)d_ws;
    hipLaunchKernelGGL(wtrans_kernel, dim3(16, 6), dim3(256), 0, stream,
                       Wq, Wk, Wv, Wqs, Wks, Wvs, ws);
    hipLaunchKernelGGL(proj_kernel, dim3(136, 2, 3), dim3(256), 0, stream, x, ws);
    hipLaunchKernelGGL(attn_kernel, dim3(544, 2), dim3(1024), 0, stream, ws, cope, scl, outp);
  }
}